// Round 1
// baseline (2639.114 us; speedup 1.0000x reference)
//
#include <hip/hip_runtime.h>
#include <math.h>

#define HID 64
#define IN_DIM 256

// ---------------- degree / norm ----------------
__global__ __launch_bounds__(256) void deg_kernel(const int* __restrict__ dst, int E,
                                                  float* __restrict__ deg) {
    int e = blockIdx.x * blockDim.x + threadIdx.x;
    if (e < E) atomicAdd(&deg[dst[e]], 1.0f);
}

__global__ __launch_bounds__(256) void dinv_kernel(float* __restrict__ dinv, int N) {
    int v = blockIdx.x * blockDim.x + threadIdx.x;
    if (v < N) dinv[v] = rsqrtf(dinv[v] + 1.0f);  // +1 for self-loop
}

// ---------------- GEMM: t = x @ W  ([N,K] @ [K,64]) ----------------
// one thread per (n, j); wave covers one node row (j = lane)
__global__ __launch_bounds__(256) void gemm_k256(const float* __restrict__ x,
                                                 const float* __restrict__ W,
                                                 float* __restrict__ t, int N) {
    long tid = (long)blockIdx.x * blockDim.x + threadIdx.x;
    int n = (int)(tid >> 6), j = (int)(tid & 63);
    if (n >= N) return;
    const float* xr = x + (size_t)n * IN_DIM;
    float acc = 0.f;
#pragma unroll
    for (int k = 0; k < IN_DIM; k += 4) {
        float4 xv = *(const float4*)(xr + k);
        acc = fmaf(xv.x, W[(k + 0) * HID + j], acc);
        acc = fmaf(xv.y, W[(k + 1) * HID + j], acc);
        acc = fmaf(xv.z, W[(k + 2) * HID + j], acc);
        acc = fmaf(xv.w, W[(k + 3) * HID + j], acc);
    }
    t[(size_t)n * HID + j] = acc;
}

__global__ __launch_bounds__(256) void gemm_k64(const float* __restrict__ h,
                                                const float* __restrict__ W,
                                                float* __restrict__ t, int N) {
    long tid = (long)blockIdx.x * blockDim.x + threadIdx.x;
    int n = (int)(tid >> 6), j = (int)(tid & 63);
    if (n >= N) return;
    const float* hr = h + (size_t)n * HID;
    float acc = 0.f;
#pragma unroll
    for (int k = 0; k < HID; k += 4) {
        float4 hv = *(const float4*)(hr + k);
        acc = fmaf(hv.x, W[(k + 0) * HID + j], acc);
        acc = fmaf(hv.y, W[(k + 1) * HID + j], acc);
        acc = fmaf(hv.z, W[(k + 2) * HID + j], acc);
        acc = fmaf(hv.w, W[(k + 3) * HID + j], acc);
    }
    t[(size_t)n * HID + j] = acc;
}

// ---------------- edge scatter: out[dst] += t[src] * dinv[src]*dinv[dst] ----------------
__global__ __launch_bounds__(256) void scatter_kernel(const int* __restrict__ src,
                                                      const int* __restrict__ dst,
                                                      const float* __restrict__ dinv,
                                                      const float* __restrict__ t,
                                                      float* __restrict__ out, int E) {
    long tid = (long)blockIdx.x * blockDim.x + threadIdx.x;
    int e = (int)(tid >> 6), j = (int)(tid & 63);
    if (e >= E) return;
    int s = src[e], d = dst[e];
    float norm = dinv[s] * dinv[d];
    atomicAdd(&out[(size_t)d * HID + j], t[(size_t)s * HID + j] * norm);
}

// ---------------- self-loop + bias (+ optional relu) ----------------
__global__ __launch_bounds__(256) void finalize_kernel(const float* __restrict__ t,
                                                       const float* __restrict__ dinv,
                                                       const float* __restrict__ bias,
                                                       float* __restrict__ h, int N,
                                                       int do_relu) {
    long tid = (long)blockIdx.x * blockDim.x + threadIdx.x;
    int v = (int)(tid >> 6), j = (int)(tid & 63);
    if (v >= N) return;
    float dv = dinv[v];
    size_t idx = (size_t)v * HID + j;
    float val = h[idx] + t[idx] * dv * dv + bias[j];
    h[idx] = do_relu ? fmaxf(val, 0.f) : val;
}

// ---------------- a = z @ Wl1[:64], b = z @ Wl1[64:] ----------------
__global__ __launch_bounds__(256) void gemm_ab_kernel(const float* __restrict__ z,
                                                      const float* __restrict__ Wl1,
                                                      float* __restrict__ a,
                                                      float* __restrict__ b, int N) {
    long tid = (long)blockIdx.x * blockDim.x + threadIdx.x;
    int n = (int)(tid >> 6), j = (int)(tid & 63);
    if (n >= N) return;
    const float* zr = z + (size_t)n * HID;
    float acc_a = 0.f, acc_b = 0.f;
#pragma unroll
    for (int k = 0; k < HID; ++k) {
        float zv = zr[k];
        acc_a = fmaf(zv, Wl1[k * HID + j], acc_a);
        acc_b = fmaf(zv, Wl1[(k + HID) * HID + j], acc_b);
    }
    a[(size_t)n * HID + j] = acc_a;
    b[(size_t)n * HID + j] = acc_b;
}

// ---------------- decode: out[e] = sigmoid(relu(a[s]+b[d]+bl1) . Wl2 + bl2) ----------------
__global__ __launch_bounds__(256) void decode_kernel(const int* __restrict__ src,
                                                     const int* __restrict__ dst,
                                                     const float* __restrict__ a,
                                                     const float* __restrict__ b,
                                                     const float* __restrict__ bl1,
                                                     const float* __restrict__ Wl2,
                                                     const float* __restrict__ bl2,
                                                     float* __restrict__ out, int E) {
    long tid = (long)blockIdx.x * blockDim.x + threadIdx.x;
    int e = (int)(tid >> 6), j = (int)(tid & 63);
    if (e >= E) return;
    int s = src[e], d = dst[e];
    float p = a[(size_t)s * HID + j] + b[(size_t)d * HID + j] + bl1[j];
    p = fmaxf(p, 0.f) * Wl2[j];
#pragma unroll
    for (int off = 32; off; off >>= 1) p += __shfl_down(p, off, 64);
    if (j == 0) out[e] = 1.f / (1.f + expf(-(p + bl2[0])));
}

extern "C" void kernel_launch(void* const* d_in, const int* in_sizes, int n_in,
                              void* d_out, int out_size, void* d_ws, size_t ws_size,
                              hipStream_t stream) {
    const float* x   = (const float*)d_in[0];
    const int*   ei  = (const int*)d_in[1];
    const float* W1  = (const float*)d_in[2];
    const float* b1  = (const float*)d_in[3];
    const float* W2  = (const float*)d_in[4];
    const float* b2  = (const float*)d_in[5];
    const float* Wl1 = (const float*)d_in[6];
    const float* bl1 = (const float*)d_in[7];
    const float* Wl2 = (const float*)d_in[8];
    const float* bl2 = (const float*)d_in[9];
    float* out = (float*)d_out;

    const int N = in_sizes[0] / IN_DIM;   // 100000
    const int E = in_sizes[1] / 2;        // 3200000
    const int* src = ei;
    const int* dst = ei + E;

    // workspace layout (floats)
    float* ws   = (float*)d_ws;
    float* dinv = ws;                          // N
    float* t    = dinv + N;                    // N*64  (t1 then t2)
    float* h    = t + (size_t)N * HID;         // N*64  (h/hr then z)
    float* a    = h + (size_t)N * HID;         // N*64
    float* b    = a + (size_t)N * HID;         // N*64

    const int TPB = 256;
    long nodeT = (long)N * HID;
    int nodeBlocks = (int)((nodeT + TPB - 1) / TPB);
    long edgeT = (long)E * HID;
    int edgeBlocks = (int)((edgeT + TPB - 1) / TPB);

    // degrees -> dinv
    hipMemsetAsync(dinv, 0, (size_t)N * sizeof(float), stream);
    deg_kernel<<<(E + TPB - 1) / TPB, TPB, 0, stream>>>(dst, E, dinv);
    dinv_kernel<<<(N + TPB - 1) / TPB, TPB, 0, stream>>>(dinv, N);

    // conv1: t1 = x@W1 ; h = scatter + selfloop + b1 ; relu
    gemm_k256<<<nodeBlocks, TPB, 0, stream>>>(x, W1, t, N);
    hipMemsetAsync(h, 0, (size_t)N * HID * sizeof(float), stream);
    scatter_kernel<<<edgeBlocks, TPB, 0, stream>>>(src, dst, dinv, t, h, E);
    finalize_kernel<<<nodeBlocks, TPB, 0, stream>>>(t, dinv, b1, h, N, 1);

    // conv2: t2 = h@W2 ; z = scatter + selfloop + b2 (no relu), reuse h buffer
    gemm_k64<<<nodeBlocks, TPB, 0, stream>>>(h, W2, t, N);
    hipMemsetAsync(h, 0, (size_t)N * HID * sizeof(float), stream);
    scatter_kernel<<<edgeBlocks, TPB, 0, stream>>>(src, dst, dinv, t, h, E);
    finalize_kernel<<<nodeBlocks, TPB, 0, stream>>>(t, dinv, b2, h, N, 0);

    // decoder precompute: a = z@Wl1_top, b = z@Wl1_bot
    gemm_ab_kernel<<<nodeBlocks, TPB, 0, stream>>>(h, Wl1, a, b, N);

    // per-edge decode
    decode_kernel<<<edgeBlocks, TPB, 0, stream>>>(src, dst, a, b, bl1, Wl2, bl2, out, E);
}

// Round 2
// 1979.663 us; speedup vs baseline: 1.3331x; 1.3331x over previous
//
#include <hip/hip_runtime.h>
#include <math.h>

#define HID 64
#define IN_DIM 256

// ---------------- degree histogram (int) ----------------
__global__ __launch_bounds__(256) void deg_kernel(const int* __restrict__ dst, int E,
                                                  int* __restrict__ deg) {
    int e = blockIdx.x * blockDim.x + threadIdx.x;
    if (e < E) atomicAdd(&deg[dst[e]], 1);
}

__global__ __launch_bounds__(256) void dinv_kernel(const int* __restrict__ deg,
                                                   float* __restrict__ dinv, int N) {
    int v = blockIdx.x * blockDim.x + threadIdx.x;
    if (v < N) dinv[v] = rsqrtf((float)deg[v] + 1.0f);  // +1 self-loop
}

// ---------------- single-block exclusive scan: off[0..N], off[N]=E ----------------
__global__ __launch_bounds__(1024) void scan_kernel(const int* __restrict__ deg,
                                                    int* __restrict__ off, int N) {
    __shared__ int wsum[16];
    __shared__ int carry;
    int lane = threadIdx.x & 63, wid = threadIdx.x >> 6;
    if (threadIdx.x == 0) carry = 0;
    __syncthreads();
    for (int base = 0; base < N; base += 1024) {
        int i = base + threadIdx.x;
        int v = (i < N) ? deg[i] : 0;
        int incl = v;
#pragma unroll
        for (int s = 1; s < 64; s <<= 1) {
            int t = __shfl_up(incl, s, 64);
            if (lane >= s) incl += t;
        }
        if (lane == 63) wsum[wid] = incl;
        __syncthreads();
        int woff = 0;
        for (int w = 0; w < wid; ++w) woff += wsum[w];
        if (i < N) off[i] = carry + woff + incl - v;  // exclusive
        __syncthreads();
        if (threadIdx.x == 0) {
            int tot = 0;
            for (int w = 0; w < 16; ++w) tot += wsum[w];
            carry += tot;
        }
        __syncthreads();
    }
    if (threadIdx.x == 0) off[N] = carry;
}

// ---------------- CSR fill: csr_src[pos] = src, grouped by dst ----------------
__global__ __launch_bounds__(256) void fill_kernel(const int* __restrict__ src,
                                                   const int* __restrict__ dst,
                                                   int* __restrict__ cursor,
                                                   int* __restrict__ csr_src, int E) {
    int e = blockIdx.x * blockDim.x + threadIdx.x;
    if (e < E) {
        int pos = atomicAdd(&cursor[dst[e]], 1);
        csr_src[pos] = src[e];
    }
}

// ---------------- GEMM: t = (x @ W) * dinv[n]  ([N,K] @ [K,64]) ----------------
__global__ __launch_bounds__(256) void gemm_k256(const float* __restrict__ x,
                                                 const float* __restrict__ W,
                                                 const float* __restrict__ dinv,
                                                 float* __restrict__ t, int N) {
    long tid = (long)blockIdx.x * blockDim.x + threadIdx.x;
    int n = (int)(tid >> 6), j = (int)(tid & 63);
    if (n >= N) return;
    const float* xr = x + (size_t)n * IN_DIM;
    float acc = 0.f;
#pragma unroll
    for (int k = 0; k < IN_DIM; k += 4) {
        float4 xv = *(const float4*)(xr + k);
        acc = fmaf(xv.x, W[(k + 0) * HID + j], acc);
        acc = fmaf(xv.y, W[(k + 1) * HID + j], acc);
        acc = fmaf(xv.z, W[(k + 2) * HID + j], acc);
        acc = fmaf(xv.w, W[(k + 3) * HID + j], acc);
    }
    t[(size_t)n * HID + j] = acc * dinv[n];
}

__global__ __launch_bounds__(256) void gemm_k64(const float* __restrict__ h,
                                                const float* __restrict__ W,
                                                const float* __restrict__ dinv,
                                                float* __restrict__ t, int N) {
    long tid = (long)blockIdx.x * blockDim.x + threadIdx.x;
    int n = (int)(tid >> 6), j = (int)(tid & 63);
    if (n >= N) return;
    const float* hr = h + (size_t)n * HID;
    float acc = 0.f;
#pragma unroll
    for (int k = 0; k < HID; k += 4) {
        float4 hv = *(const float4*)(hr + k);
        acc = fmaf(hv.x, W[(k + 0) * HID + j], acc);
        acc = fmaf(hv.y, W[(k + 1) * HID + j], acc);
        acc = fmaf(hv.z, W[(k + 2) * HID + j], acc);
        acc = fmaf(hv.w, W[(k + 3) * HID + j], acc);
    }
    t[(size_t)n * HID + j] = acc * dinv[n];
}

// ---------------- gather: h[v] = relu?( dinv[v]*(sum_in ts[s] + ts[v]) + bias ) ----------------
// ts is already scaled by dinv[src]; one wave per node, lane = feature.
__global__ __launch_bounds__(256) void gather_kernel(const int* __restrict__ off,
                                                     const int* __restrict__ csr_src,
                                                     const float* __restrict__ ts,
                                                     const float* __restrict__ dinv,
                                                     const float* __restrict__ bias,
                                                     float* __restrict__ outh, int N,
                                                     int do_relu) {
    long tid = (long)blockIdx.x * blockDim.x + threadIdx.x;
    int v = (int)(tid >> 6), j = (int)(tid & 63);
    if (v >= N) return;
    int beg = off[v], end = off[v + 1];
    float acc = ts[(size_t)v * HID + j];  // self-loop term (pre-scaled by dinv[v])
    for (int i = beg; i < end; i += 64) {
        int nchunk = end - i;
        if (nchunk > 64) nchunk = 64;
        int eid = (i + j < end) ? csr_src[i + j] : 0;
        for (int k = 0; k < nchunk; ++k) {
            int s = __shfl(eid, k, 64);
            acc += ts[(size_t)s * HID + j];
        }
    }
    float val = acc * dinv[v] + bias[j];
    outh[(size_t)v * HID + j] = do_relu ? fmaxf(val, 0.f) : val;
}

// ---------------- a = z @ Wl1[:64], b = z @ Wl1[64:] ----------------
__global__ __launch_bounds__(256) void gemm_ab_kernel(const float* __restrict__ z,
                                                      const float* __restrict__ Wl1,
                                                      float* __restrict__ a,
                                                      float* __restrict__ b, int N) {
    long tid = (long)blockIdx.x * blockDim.x + threadIdx.x;
    int n = (int)(tid >> 6), j = (int)(tid & 63);
    if (n >= N) return;
    const float* zr = z + (size_t)n * HID;
    float acc_a = 0.f, acc_b = 0.f;
#pragma unroll
    for (int k = 0; k < HID; ++k) {
        float zv = zr[k];
        acc_a = fmaf(zv, Wl1[k * HID + j], acc_a);
        acc_b = fmaf(zv, Wl1[(k + HID) * HID + j], acc_b);
    }
    a[(size_t)n * HID + j] = acc_a;
    b[(size_t)n * HID + j] = acc_b;
}

// ---------------- decode: out[e] = sigmoid(relu(a[s]+b[d]+bl1) . Wl2 + bl2) ----------------
__global__ __launch_bounds__(256) void decode_kernel(const int* __restrict__ src,
                                                     const int* __restrict__ dst,
                                                     const float* __restrict__ a,
                                                     const float* __restrict__ b,
                                                     const float* __restrict__ bl1,
                                                     const float* __restrict__ Wl2,
                                                     const float* __restrict__ bl2,
                                                     float* __restrict__ out, int E) {
    long tid = (long)blockIdx.x * blockDim.x + threadIdx.x;
    int e = (int)(tid >> 6), j = (int)(tid & 63);
    if (e >= E) return;
    int s = src[e], d = dst[e];
    float p = a[(size_t)s * HID + j] + b[(size_t)d * HID + j] + bl1[j];
    p = fmaxf(p, 0.f) * Wl2[j];
#pragma unroll
    for (int off = 32; off; off >>= 1) p += __shfl_down(p, off, 64);
    if (j == 0) out[e] = 1.f / (1.f + expf(-(p + bl2[0])));
}

extern "C" void kernel_launch(void* const* d_in, const int* in_sizes, int n_in,
                              void* d_out, int out_size, void* d_ws, size_t ws_size,
                              hipStream_t stream) {
    const float* x   = (const float*)d_in[0];
    const int*   ei  = (const int*)d_in[1];
    const float* W1  = (const float*)d_in[2];
    const float* b1  = (const float*)d_in[3];
    const float* W2  = (const float*)d_in[4];
    const float* b2  = (const float*)d_in[5];
    const float* Wl1 = (const float*)d_in[6];
    const float* bl1 = (const float*)d_in[7];
    const float* Wl2 = (const float*)d_in[8];
    const float* bl2 = (const float*)d_in[9];
    float* out = (float*)d_out;

    const int N = in_sizes[0] / IN_DIM;   // 100000
    const int E = in_sizes[1] / 2;        // 3200000
    const int* src = ei;
    const int* dst = ei + E;

    // workspace layout
    char* ws = (char*)d_ws;
    int*   deg    = (int*)ws;                          ws += (size_t)(N + 64) * 4;
    int*   off    = (int*)ws;                          ws += (size_t)(N + 64) * 4;
    int*   cursor = (int*)ws;                          ws += (size_t)(N + 64) * 4;
    int*   csr    = (int*)ws;                          ws += (size_t)E * 4;
    float* dinv   = (float*)ws;                        ws += (size_t)(N + 64) * 4;
    float* t      = (float*)ws;                        ws += (size_t)N * HID * 4;  // t1/t2, then a
    float* h      = (float*)ws;                        ws += (size_t)N * HID * 4;  // h, then z
    float* b      = (float*)ws;                        ws += (size_t)N * HID * 4;

    const int TPB = 256;
    long nodeT = (long)N * HID;
    int nodeBlocks = (int)((nodeT + TPB - 1) / TPB);
    long edgeT = (long)E * HID;
    int edgeBlocks = (int)((edgeT + TPB - 1) / TPB);
    int eBlocks = (E + TPB - 1) / TPB;
    int nBlocks = (N + TPB - 1) / TPB;

    // ---- CSR build (shared by both convs) ----
    hipMemsetAsync(deg, 0, (size_t)N * sizeof(int), stream);
    deg_kernel<<<eBlocks, TPB, 0, stream>>>(dst, E, deg);
    dinv_kernel<<<nBlocks, TPB, 0, stream>>>(deg, dinv, N);
    scan_kernel<<<1, 1024, 0, stream>>>(deg, off, N);
    hipMemcpyAsync(cursor, off, (size_t)N * sizeof(int), hipMemcpyDeviceToDevice, stream);
    fill_kernel<<<eBlocks, TPB, 0, stream>>>(src, dst, cursor, csr, E);

    // ---- conv1: t1 = (x@W1)*dinv ; h = relu(gather + self + b1) ----
    gemm_k256<<<nodeBlocks, TPB, 0, stream>>>(x, W1, dinv, t, N);
    gather_kernel<<<nodeBlocks, TPB, 0, stream>>>(off, csr, t, dinv, b1, h, N, 1);

    // ---- conv2: t2 = (h@W2)*dinv ; z = gather + self + b2 (into h) ----
    gemm_k64<<<nodeBlocks, TPB, 0, stream>>>(h, W2, dinv, t, N);
    gather_kernel<<<nodeBlocks, TPB, 0, stream>>>(off, csr, t, dinv, b2, h, N, 0);

    // ---- decoder precompute: a = z@Wl1_top (into t), b = z@Wl1_bot ----
    gemm_ab_kernel<<<nodeBlocks, TPB, 0, stream>>>(h, Wl1, t, b, N);

    // ---- per-edge decode ----
    decode_kernel<<<edgeBlocks, TPB, 0, stream>>>(src, dst, t, b, bl1, Wl2, bl2, out, E);
}

// Round 3
// 1657.662 us; speedup vs baseline: 1.5921x; 1.1943x over previous
//
#include <hip/hip_runtime.h>
#include <hip/hip_bf16.h>
#include <math.h>

#define HID 64
#define IN_DIM 256

typedef unsigned short u16;
typedef unsigned int u32;

__device__ __forceinline__ float bf2f(u16 v) {
    return __uint_as_float((u32)v << 16);
}
__device__ __forceinline__ u16 f2bf(float f) {
    __hip_bfloat16 b = __float2bfloat16(f);  // RNE
    return *(u16*)&b;
}

// ---------------- degree histogram ----------------
__global__ __launch_bounds__(256) void deg_kernel(const int* __restrict__ dst, int E,
                                                  int* __restrict__ deg) {
    int e = blockIdx.x * blockDim.x + threadIdx.x;
    if (e < E) atomicAdd(&deg[dst[e]], 1);
}

__global__ __launch_bounds__(256) void dinv_kernel(const int* __restrict__ deg,
                                                   float* __restrict__ dinv, int N) {
    int v = blockIdx.x * blockDim.x + threadIdx.x;
    if (v < N) dinv[v] = rsqrtf((float)deg[v] + 1.0f);  // +1 self-loop
}

// ---------------- single-block exclusive scan ----------------
__global__ __launch_bounds__(1024) void scan_kernel(const int* __restrict__ deg,
                                                    int* __restrict__ off, int N) {
    __shared__ int wsum[16];
    __shared__ int carry;
    int lane = threadIdx.x & 63, wid = threadIdx.x >> 6;
    if (threadIdx.x == 0) carry = 0;
    __syncthreads();
    for (int base = 0; base < N; base += 1024) {
        int i = base + threadIdx.x;
        int v = (i < N) ? deg[i] : 0;
        int incl = v;
#pragma unroll
        for (int s = 1; s < 64; s <<= 1) {
            int t = __shfl_up(incl, s, 64);
            if (lane >= s) incl += t;
        }
        if (lane == 63) wsum[wid] = incl;
        __syncthreads();
        int woff = 0;
        for (int w = 0; w < wid; ++w) woff += wsum[w];
        if (i < N) off[i] = carry + woff + incl - v;  // exclusive
        __syncthreads();
        if (threadIdx.x == 0) {
            int tot = 0;
            for (int w = 0; w < 16; ++w) tot += wsum[w];
            carry += tot;
        }
        __syncthreads();
    }
    if (threadIdx.x == 0) off[N] = carry;
}

// ---------------- CSR fill: pair[pos] = {src, orig_eid}, grouped by dst ----------------
__global__ __launch_bounds__(256) void fill_kernel(const int* __restrict__ src,
                                                   const int* __restrict__ dst,
                                                   int* __restrict__ cursor,
                                                   int2* __restrict__ pair, int E) {
    int e = blockIdx.x * blockDim.x + threadIdx.x;
    if (e < E) {
        int pos = atomicAdd(&cursor[dst[e]], 1);
        pair[pos] = make_int2(src[e], e);
    }
}

// ---------------- GEMM: t = bf16((x @ W) * dinv[n]) ----------------
__global__ __launch_bounds__(256) void gemm_k256(const float* __restrict__ x,
                                                 const float* __restrict__ W,
                                                 const float* __restrict__ dinv,
                                                 u16* __restrict__ t, int N) {
    long tid = (long)blockIdx.x * blockDim.x + threadIdx.x;
    int n = (int)(tid >> 6), j = (int)(tid & 63);
    if (n >= N) return;
    const float* xr = x + (size_t)n * IN_DIM;
    float acc = 0.f;
#pragma unroll
    for (int k = 0; k < IN_DIM; k += 4) {
        float4 xv = *(const float4*)(xr + k);
        acc = fmaf(xv.x, W[(k + 0) * HID + j], acc);
        acc = fmaf(xv.y, W[(k + 1) * HID + j], acc);
        acc = fmaf(xv.z, W[(k + 2) * HID + j], acc);
        acc = fmaf(xv.w, W[(k + 3) * HID + j], acc);
    }
    t[(size_t)n * HID + j] = f2bf(acc * dinv[n]);
}

__global__ __launch_bounds__(256) void gemm_k64(const float* __restrict__ h,
                                                const float* __restrict__ W,
                                                const float* __restrict__ dinv,
                                                u16* __restrict__ t, int N) {
    long tid = (long)blockIdx.x * blockDim.x + threadIdx.x;
    int n = (int)(tid >> 6), j = (int)(tid & 63);
    if (n >= N) return;
    const float* hr = h + (size_t)n * HID;
    float acc = 0.f;
#pragma unroll
    for (int k = 0; k < HID; k += 4) {
        float4 hv = *(const float4*)(hr + k);
        acc = fmaf(hv.x, W[(k + 0) * HID + j], acc);
        acc = fmaf(hv.y, W[(k + 1) * HID + j], acc);
        acc = fmaf(hv.z, W[(k + 2) * HID + j], acc);
        acc = fmaf(hv.w, W[(k + 3) * HID + j], acc);
    }
    t[(size_t)n * HID + j] = f2bf(acc * dinv[n]);
}

// ---------------- gather: h[v] = relu?( dinv[v]*(sum_in ts[s] + ts[v]) + bias ) ----------------
__global__ __launch_bounds__(256) void gather_kernel(const int* __restrict__ off,
                                                     const int2* __restrict__ pair,
                                                     const u16* __restrict__ ts,
                                                     const float* __restrict__ dinv,
                                                     const float* __restrict__ bias,
                                                     float* __restrict__ outh, int N,
                                                     int do_relu) {
    long tid = (long)blockIdx.x * blockDim.x + threadIdx.x;
    int v = (int)(tid >> 6), j = (int)(tid & 63);
    if (v >= N) return;
    int beg = off[v], end = off[v + 1];
    float acc = bf2f(ts[(size_t)v * HID + j]);  // self-loop (pre-scaled by dinv[v])
    for (int i = beg; i < end; i += 64) {
        int idx = i + j;
        int sj = (idx < end) ? pair[idx].x : 0;
        int m = end - i;
        if (m > 64) m = 64;
        for (int k = 0; k < m; ++k) {
            int s = __shfl(sj, k, 64);
            acc += bf2f(ts[(size_t)s * HID + j]);
        }
    }
    float val = acc * dinv[v] + bias[j];
    outh[(size_t)v * HID + j] = do_relu ? fmaxf(val, 0.f) : val;
}

// ---------------- a = bf16(z @ Wl1[:64]), c = z @ Wl1[64:] + bl1 ----------------
__global__ __launch_bounds__(256) void gemm_ab_kernel(const float* __restrict__ z,
                                                      const float* __restrict__ Wl1,
                                                      const float* __restrict__ bl1,
                                                      u16* __restrict__ a,
                                                      float* __restrict__ c, int N) {
    long tid = (long)blockIdx.x * blockDim.x + threadIdx.x;
    int n = (int)(tid >> 6), j = (int)(tid & 63);
    if (n >= N) return;
    const float* zr = z + (size_t)n * HID;
    float acc_a = 0.f, acc_b = 0.f;
#pragma unroll
    for (int k = 0; k < HID; ++k) {
        float zv = zr[k];
        acc_a = fmaf(zv, Wl1[k * HID + j], acc_a);
        acc_b = fmaf(zv, Wl1[(k + HID) * HID + j], acc_b);
    }
    a[(size_t)n * HID + j] = f2bf(acc_a);
    c[(size_t)n * HID + j] = acc_b + bl1[j];
}

// ---------------- node-centric decode ----------------
// wave per dst node d; half-wave per edge, 2 features per lane (packed bf16).
// out[eid] = sigmoid( sum_j relu(a[s][j] + c[d][j]) * Wl2[j] + bl2 )
__global__ __launch_bounds__(256) void decode_kernel(const int* __restrict__ off,
                                                     const int2* __restrict__ pair,
                                                     const u16* __restrict__ a,
                                                     const float* __restrict__ c,
                                                     const float* __restrict__ Wl2,
                                                     const float* __restrict__ bl2,
                                                     float* __restrict__ out, int N) {
    long tid = (long)blockIdx.x * blockDim.x + threadIdx.x;
    int v = (int)(tid >> 6), j = (int)(tid & 63);
    if (v >= N) return;
    int l = j & 31, h = j >> 5;
    // per-lane constants: features 2l, 2l+1 of node v
    float2 c2 = *(const float2*)(c + (size_t)v * HID + 2 * l);
    float2 w2 = *(const float2*)(Wl2 + 2 * l);
    float bl2v = bl2[0];
    int beg = off[v], end = off[v + 1];
    for (int i0 = beg; i0 < end; i0 += 64) {
        int idx = i0 + j;
        int2 pr = (idx < end) ? pair[idx] : make_int2(0, 0);
        int m = end - i0;
        if (m > 64) m = 64;
        for (int k = 0; k < m; k += 2) {
            int kk = k + h;  // this half-wave's edge slot
            int s   = __shfl(pr.x, kk, 64);
            int eid = __shfl(pr.y, kk, 64);
            bool act = kk < m;
            float p = 0.f;
            if (act) {
                u32 u = *(const u32*)(a + (size_t)s * HID + 2 * l);
                float f0 = __uint_as_float(u << 16);
                float f1 = __uint_as_float(u & 0xffff0000u);
                p = fmaxf(f0 + c2.x, 0.f) * w2.x + fmaxf(f1 + c2.y, 0.f) * w2.y;
            }
#pragma unroll
            for (int o = 16; o; o >>= 1) p += __shfl_xor(p, o, 64);  // 32-lane half reduce
            if (act && l == 0) out[eid] = 1.f / (1.f + expf(-(p + bl2v)));
        }
    }
}

extern "C" void kernel_launch(void* const* d_in, const int* in_sizes, int n_in,
                              void* d_out, int out_size, void* d_ws, size_t ws_size,
                              hipStream_t stream) {
    const float* x   = (const float*)d_in[0];
    const int*   ei  = (const int*)d_in[1];
    const float* W1  = (const float*)d_in[2];
    const float* b1  = (const float*)d_in[3];
    const float* W2  = (const float*)d_in[4];
    const float* b2  = (const float*)d_in[5];
    const float* Wl1 = (const float*)d_in[6];
    const float* bl1 = (const float*)d_in[7];
    const float* Wl2 = (const float*)d_in[8];
    const float* bl2 = (const float*)d_in[9];
    float* out = (float*)d_out;

    const int N = in_sizes[0] / IN_DIM;   // 100000
    const int E = in_sizes[1] / 2;        // 3200000
    const int* src = ei;
    const int* dst = ei + E;

    // workspace layout
    char* ws = (char*)d_ws;
    int*   deg    = (int*)ws;     ws += (size_t)(N + 64) * 4;
    int*   off    = (int*)ws;     ws += (size_t)(N + 64) * 4;
    int*   cursor = (int*)ws;     ws += (size_t)(N + 64) * 4;
    int2*  pair   = (int2*)ws;    ws += (size_t)E * 8;
    float* dinv   = (float*)ws;   ws += (size_t)(N + 64) * 4;
    u16*   tb     = (u16*)ws;     ws += (size_t)N * HID * 2;   // t1, t2, then a (bf16)
    float* h      = (float*)ws;   ws += (size_t)N * HID * 4;   // h, then z
    float* c      = (float*)ws;   ws += (size_t)N * HID * 4;

    const int TPB = 256;
    long nodeT = (long)N * HID;
    int nodeBlocks = (int)((nodeT + TPB - 1) / TPB);
    int eBlocks = (E + TPB - 1) / TPB;
    int nBlocks = (N + TPB - 1) / TPB;

    // ---- CSR build ----
    hipMemsetAsync(deg, 0, (size_t)N * sizeof(int), stream);
    deg_kernel<<<eBlocks, TPB, 0, stream>>>(dst, E, deg);
    dinv_kernel<<<nBlocks, TPB, 0, stream>>>(deg, dinv, N);
    scan_kernel<<<1, 1024, 0, stream>>>(deg, off, N);
    hipMemcpyAsync(cursor, off, (size_t)N * sizeof(int), hipMemcpyDeviceToDevice, stream);
    fill_kernel<<<eBlocks, TPB, 0, stream>>>(src, dst, cursor, pair, E);

    // ---- conv1 ----
    gemm_k256<<<nodeBlocks, TPB, 0, stream>>>(x, W1, dinv, tb, N);
    gather_kernel<<<nodeBlocks, TPB, 0, stream>>>(off, pair, tb, dinv, b1, h, N, 1);

    // ---- conv2 (z into h) ----
    gemm_k64<<<nodeBlocks, TPB, 0, stream>>>(h, W2, dinv, tb, N);
    gather_kernel<<<nodeBlocks, TPB, 0, stream>>>(off, pair, tb, dinv, b2, h, N, 0);

    // ---- decoder precompute: a (bf16, into tb), c = zWl1_bot + bl1 ----
    gemm_ab_kernel<<<nodeBlocks, TPB, 0, stream>>>(h, Wl1, bl1, tb, c, N);

    // ---- node-centric decode ----
    decode_kernel<<<nodeBlocks, TPB, 0, stream>>>(off, pair, tb, c, Wl2, bl2, out, N);
}

// Round 4
// 1195.475 us; speedup vs baseline: 2.2076x; 1.3866x over previous
//
#include <hip/hip_runtime.h>
#include <hip/hip_bf16.h>
#include <math.h>

#define HID 64
#define IN_DIM 256

typedef unsigned short u16;
typedef unsigned int u32;

using bf16x8 = __attribute__((ext_vector_type(8))) short;
using f32x4  = __attribute__((ext_vector_type(4))) float;

__device__ __forceinline__ float bf2f(u16 v) {
    return __uint_as_float((u32)v << 16);
}
__device__ __forceinline__ u16 f2bf(float f) {
    __hip_bfloat16 b = __float2bfloat16(f);  // RNE
    return *(u16*)&b;
}

// ---------------- degree histogram ----------------
__global__ __launch_bounds__(256) void deg_kernel(const int* __restrict__ dst, int E,
                                                  int* __restrict__ deg) {
    int e = blockIdx.x * blockDim.x + threadIdx.x;
    if (e < E) atomicAdd(&deg[dst[e]], 1);
}

__global__ __launch_bounds__(256) void dinv_kernel(const int* __restrict__ deg,
                                                   float* __restrict__ dinv, int N) {
    int v = blockIdx.x * blockDim.x + threadIdx.x;
    if (v < N) dinv[v] = rsqrtf((float)deg[v] + 1.0f);  // +1 self-loop
}

// ---------------- single-block exclusive scan ----------------
__global__ __launch_bounds__(1024) void scan_kernel(const int* __restrict__ deg,
                                                    int* __restrict__ off, int N) {
    __shared__ int wsum[16];
    __shared__ int carry;
    int lane = threadIdx.x & 63, wid = threadIdx.x >> 6;
    if (threadIdx.x == 0) carry = 0;
    __syncthreads();
    for (int base = 0; base < N; base += 1024) {
        int i = base + threadIdx.x;
        int v = (i < N) ? deg[i] : 0;
        int incl = v;
#pragma unroll
        for (int s = 1; s < 64; s <<= 1) {
            int t = __shfl_up(incl, s, 64);
            if (lane >= s) incl += t;
        }
        if (lane == 63) wsum[wid] = incl;
        __syncthreads();
        int woff = 0;
        for (int w = 0; w < wid; ++w) woff += wsum[w];
        if (i < N) off[i] = carry + woff + incl - v;  // exclusive
        __syncthreads();
        if (threadIdx.x == 0) {
            int tot = 0;
            for (int w = 0; w < 16; ++w) tot += wsum[w];
            carry += tot;
        }
        __syncthreads();
    }
    if (threadIdx.x == 0) off[N] = carry;
}

// ---------------- CSR fill: pair[pos] = {src, orig_eid}, grouped by dst ----------------
__global__ __launch_bounds__(256) void fill_kernel(const int* __restrict__ src,
                                                   const int* __restrict__ dst,
                                                   int* __restrict__ cursor,
                                                   int2* __restrict__ pair, int E) {
    int e = blockIdx.x * blockDim.x + threadIdx.x;
    if (e < E) {
        int pos = atomicAdd(&cursor[dst[e]], 1);
        pair[pos] = make_int2(src[e], e);
    }
}

// ---------------- MFMA GEMM: out = A[N,K] @ W[K,COLS] (hi/lo split, fp32-accurate) ----
// MODE 0: out_b[n][j] = bf16(acc * dinv[n])                  (COLS=64)
// MODE 2: cols 0-63:  out_b = bf16(acc)  (a)
//         cols 64-127: out_f = acc + bias[col-64]  (c);  W is Wl1 [128][64]
template<int K, int COLS, int MODE>
__global__ __launch_bounds__(256) void mfma_gemm(const float* __restrict__ A,
                                                 const float* __restrict__ W,
                                                 const float* __restrict__ dinv,
                                                 const float* __restrict__ bias,
                                                 u16* __restrict__ out_b,
                                                 float* __restrict__ out_f,
                                                 int N) {
    constexpr int KP = K + 8;   // W^T row stride (u16): (K+8)*2B ≡ 4 mod 32 words
    constexpr int AP = 72;      // A chunk row stride (u16), KC=64
    constexpr int NT = COLS / 16;
    __shared__ __align__(16) u16 Wh[COLS * KP];
    __shared__ __align__(16) u16 Wl[COLS * KP];
    __shared__ __align__(16) u16 Ah[64 * AP];
    __shared__ __align__(16) u16 Al[64 * AP];

    const int tid  = threadIdx.x;
    const int wave = tid >> 6;
    const int lane = tid & 63;
    const int lr   = lane & 15;
    const int kg   = lane >> 4;
    const int row0 = blockIdx.x * 64;

    // ---- stage W transposed + hi/lo split ----
    for (int e = tid; e < K * COLS; e += 256) {
        int k = e / COLS, c = e % COLS;
        int gidx = (MODE == 2) ? (((c >> 6) * K + k) * 64 + (c & 63)) : e;
        float f = W[gidx];
        u16 hi = f2bf(f);
        u16 lo = f2bf(f - bf2f(hi));
        Wh[c * KP + k] = hi;
        Wl[c * KP + k] = lo;
    }

    f32x4 acc[NT];
#pragma unroll
    for (int c = 0; c < NT; ++c) acc[c] = (f32x4){0.f, 0.f, 0.f, 0.f};

    for (int kc = 0; kc < K; kc += 64) {
        __syncthreads();
        // ---- stage A chunk [64 rows][64 k] fp32 -> bf16 hi/lo ----
#pragma unroll
        for (int it = 0; it < 4; ++it) {
            int idx = it * 256 + tid;     // float4 granules: 64 rows x 16
            int r  = idx >> 4;
            int k4 = (idx & 15) * 4;
            int gr = row0 + r;
            float4 v = make_float4(0.f, 0.f, 0.f, 0.f);
            if (gr < N) v = *(const float4*)(A + (size_t)gr * K + kc + k4);
            u16 h0 = f2bf(v.x), h1 = f2bf(v.y), h2 = f2bf(v.z), h3 = f2bf(v.w);
            ushort4 hv = make_ushort4(h0, h1, h2, h3);
            ushort4 lv = make_ushort4(f2bf(v.x - bf2f(h0)), f2bf(v.y - bf2f(h1)),
                                      f2bf(v.z - bf2f(h2)), f2bf(v.w - bf2f(h3)));
            *(ushort4*)(Ah + r * AP + k4) = hv;
            *(ushort4*)(Al + r * AP + k4) = lv;
        }
        __syncthreads();
#pragma unroll
        for (int ks = 0; ks < 64; ks += 32) {
            const int arow = wave * 16 + lr;
            bf16x8 ah = *(const bf16x8*)(Ah + arow * AP + ks + kg * 8);
            bf16x8 al = *(const bf16x8*)(Al + arow * AP + ks + kg * 8);
#pragma unroll
            for (int c = 0; c < NT; ++c) {
                const int wrow = c * 16 + lr;
                bf16x8 bh = *(const bf16x8*)(Wh + wrow * KP + kc + ks + kg * 8);
                bf16x8 bl = *(const bf16x8*)(Wl + wrow * KP + kc + ks + kg * 8);
                acc[c] = __builtin_amdgcn_mfma_f32_16x16x32_bf16(ah, bh, acc[c], 0, 0, 0);
                acc[c] = __builtin_amdgcn_mfma_f32_16x16x32_bf16(ah, bl, acc[c], 0, 0, 0);
                acc[c] = __builtin_amdgcn_mfma_f32_16x16x32_bf16(al, bh, acc[c], 0, 0, 0);
            }
        }
    }

    // ---- epilogue: D row=(lane>>4)*4+reg, col=lane&15 (+16c) ----
#pragma unroll
    for (int rr = 0; rr < 4; ++rr) {
        int n = row0 + wave * 16 + kg * 4 + rr;
        if (n >= N) continue;
        float dv = (MODE == 0) ? dinv[n] : 1.f;
#pragma unroll
        for (int c = 0; c < NT; ++c) {
            int col = c * 16 + lr;
            float v = acc[c][rr];
            if (MODE == 0) {
                out_b[(size_t)n * 64 + col] = f2bf(v * dv);
            } else {
                if (col < 64) out_b[(size_t)n * 64 + col] = f2bf(v);
                else out_f[(size_t)n * 64 + (col - 64)] = v + bias[col - 64];
            }
        }
    }
}

// ---------------- gather: h[v] = relu?( dinv[v]*(sum_in ts[s] + ts[v]) + bias ) ----------------
__global__ __launch_bounds__(256) void gather_kernel(const int* __restrict__ off,
                                                     const int2* __restrict__ pair,
                                                     const u16* __restrict__ ts,
                                                     const float* __restrict__ dinv,
                                                     const float* __restrict__ bias,
                                                     float* __restrict__ outh, int N,
                                                     int do_relu) {
    long tid = (long)blockIdx.x * blockDim.x + threadIdx.x;
    int v = (int)(tid >> 6), j = (int)(tid & 63);
    if (v >= N) return;
    int beg = off[v], end = off[v + 1];
    float acc = bf2f(ts[(size_t)v * HID + j]);  // self-loop (pre-scaled by dinv[v])
    for (int i = beg; i < end; i += 64) {
        int idx = i + j;
        int sj = (idx < end) ? pair[idx].x : 0;
        int m = end - i;
        if (m > 64) m = 64;
        for (int k = 0; k < m; ++k) {
            int s = __shfl(sj, k, 64);
            acc += bf2f(ts[(size_t)s * HID + j]);
        }
    }
    float val = acc * dinv[v] + bias[j];
    outh[(size_t)v * HID + j] = do_relu ? fmaxf(val, 0.f) : val;
}

// ---------------- node-centric decode ----------------
__global__ __launch_bounds__(256) void decode_kernel(const int* __restrict__ off,
                                                     const int2* __restrict__ pair,
                                                     const u16* __restrict__ a,
                                                     const float* __restrict__ c,
                                                     const float* __restrict__ Wl2,
                                                     const float* __restrict__ bl2,
                                                     float* __restrict__ out, int N) {
    long tid = (long)blockIdx.x * blockDim.x + threadIdx.x;
    int v = (int)(tid >> 6), j = (int)(tid & 63);
    if (v >= N) return;
    int l = j & 31, h = j >> 5;
    float2 c2 = *(const float2*)(c + (size_t)v * HID + 2 * l);
    float2 w2 = *(const float2*)(Wl2 + 2 * l);
    float bl2v = bl2[0];
    int beg = off[v], end = off[v + 1];
    for (int i0 = beg; i0 < end; i0 += 64) {
        int idx = i0 + j;
        int2 pr = (idx < end) ? pair[idx] : make_int2(0, 0);
        int m = end - i0;
        if (m > 64) m = 64;
        for (int k = 0; k < m; k += 2) {
            int kk = k + h;
            int s   = __shfl(pr.x, kk, 64);
            int eid = __shfl(pr.y, kk, 64);
            bool act = kk < m;
            float p = 0.f;
            if (act) {
                u32 u = *(const u32*)(a + (size_t)s * HID + 2 * l);
                float f0 = __uint_as_float(u << 16);
                float f1 = __uint_as_float(u & 0xffff0000u);
                p = fmaxf(f0 + c2.x, 0.f) * w2.x + fmaxf(f1 + c2.y, 0.f) * w2.y;
            }
#pragma unroll
            for (int o = 16; o; o >>= 1) p += __shfl_xor(p, o, 64);
            if (act && l == 0) out[eid] = 1.f / (1.f + expf(-(p + bl2v)));
        }
    }
}

extern "C" void kernel_launch(void* const* d_in, const int* in_sizes, int n_in,
                              void* d_out, int out_size, void* d_ws, size_t ws_size,
                              hipStream_t stream) {
    const float* x   = (const float*)d_in[0];
    const int*   ei  = (const int*)d_in[1];
    const float* W1  = (const float*)d_in[2];
    const float* b1  = (const float*)d_in[3];
    const float* W2  = (const float*)d_in[4];
    const float* b2  = (const float*)d_in[5];
    const float* Wl1 = (const float*)d_in[6];
    const float* bl1 = (const float*)d_in[7];
    const float* Wl2 = (const float*)d_in[8];
    const float* bl2 = (const float*)d_in[9];
    float* out = (float*)d_out;

    const int N = in_sizes[0] / IN_DIM;   // 100000
    const int E = in_sizes[1] / 2;        // 3200000
    const int* src = ei;
    const int* dst = ei + E;

    // workspace layout
    char* ws = (char*)d_ws;
    int*   deg    = (int*)ws;     ws += (size_t)(N + 64) * 4;
    int*   off    = (int*)ws;     ws += (size_t)(N + 64) * 4;
    int*   cursor = (int*)ws;     ws += (size_t)(N + 64) * 4;
    int2*  pair   = (int2*)ws;    ws += (size_t)E * 8;
    float* dinv   = (float*)ws;   ws += (size_t)(N + 64) * 4;
    u16*   tb     = (u16*)ws;     ws += (size_t)N * HID * 2;   // t1, t2, then a (bf16)
    float* h      = (float*)ws;   ws += (size_t)N * HID * 4;   // h, then z
    float* c      = (float*)ws;   ws += (size_t)N * HID * 4;

    const int TPB = 256;
    long nodeT = (long)N * HID;
    int nodeBlocks = (int)((nodeT + TPB - 1) / TPB);
    int eBlocks = (E + TPB - 1) / TPB;
    int nBlocks = (N + TPB - 1) / TPB;
    int gBlocks = (N + 63) / 64;

    // ---- CSR build ----
    hipMemsetAsync(deg, 0, (size_t)N * sizeof(int), stream);
    deg_kernel<<<eBlocks, TPB, 0, stream>>>(dst, E, deg);
    dinv_kernel<<<nBlocks, TPB, 0, stream>>>(deg, dinv, N);
    scan_kernel<<<1, 1024, 0, stream>>>(deg, off, N);
    hipMemcpyAsync(cursor, off, (size_t)N * sizeof(int), hipMemcpyDeviceToDevice, stream);
    fill_kernel<<<eBlocks, TPB, 0, stream>>>(src, dst, cursor, pair, E);

    // ---- conv1: t1 = bf16((x@W1)*dinv) ; h = relu(gather + b1) ----
    mfma_gemm<IN_DIM, 64, 0><<<gBlocks, TPB, 0, stream>>>(x, W1, dinv, nullptr, tb, nullptr, N);
    gather_kernel<<<nodeBlocks, TPB, 0, stream>>>(off, pair, tb, dinv, b1, h, N, 1);

    // ---- conv2: t2 = bf16((h@W2)*dinv) ; z = gather + b2 (into h) ----
    mfma_gemm<HID, 64, 0><<<gBlocks, TPB, 0, stream>>>(h, W2, dinv, nullptr, tb, nullptr, N);
    gather_kernel<<<nodeBlocks, TPB, 0, stream>>>(off, pair, tb, dinv, b2, h, N, 0);

    // ---- decoder precompute: a = bf16(z@Wl1_top) into tb, c = z@Wl1_bot + bl1 ----
    mfma_gemm<HID, 128, 2><<<gBlocks, TPB, 0, stream>>>(h, Wl1, nullptr, bl1, tb, c, N);

    // ---- node-centric decode ----
    decode_kernel<<<nodeBlocks, TPB, 0, stream>>>(off, pair, tb, c, Wl2, bl2, out, N);
}

// Round 5
// 785.308 us; speedup vs baseline: 3.3606x; 1.5223x over previous
//
#include <hip/hip_runtime.h>
#include <hip/hip_bf16.h>
#include <math.h>

#define HID 64
#define IN_DIM 256
#define NPB 400          // nodes per bucket
#define NB  250          // buckets (N/NPB)
#define TILE 8192        // edges per bucket_fill block

typedef unsigned short u16;
typedef unsigned int u32;

using bf16x8 = __attribute__((ext_vector_type(8))) short;
using f32x4  = __attribute__((ext_vector_type(4))) float;

__device__ __forceinline__ float bf2f(u16 v) {
    return __uint_as_float((u32)v << 16);
}
__device__ __forceinline__ u16 f2bf(float f) {
    __hip_bfloat16 b = __float2bfloat16(f);  // RNE
    return *(u16*)&b;
}

// ---------------- degree histogram ----------------
__global__ __launch_bounds__(256) void deg_kernel(const int* __restrict__ dst, int E,
                                                  int* __restrict__ deg) {
    int e = blockIdx.x * blockDim.x + threadIdx.x;
    if (e < E) atomicAdd(&deg[dst[e]], 1);
}

__global__ __launch_bounds__(256) void dinv_kernel(const int* __restrict__ deg,
                                                   float* __restrict__ dinv, int N) {
    int v = blockIdx.x * blockDim.x + threadIdx.x;
    if (v < N) dinv[v] = rsqrtf((float)deg[v] + 1.0f);  // +1 self-loop
}

// ---------------- hierarchical exclusive scan of deg -> off ----------------
__global__ __launch_bounds__(1024) void scan_a(const int* __restrict__ deg,
                                               int* __restrict__ tsum, int N) {
    __shared__ int wsum[16];
    int t = blockIdx.x * 1024 + threadIdx.x;
    int lane = threadIdx.x & 63, wid = threadIdx.x >> 6;
    int v = (t < N) ? deg[t] : 0;
#pragma unroll
    for (int o = 32; o; o >>= 1) v += __shfl_xor(v, o, 64);
    if (lane == 0) wsum[wid] = v;
    __syncthreads();
    if (wid == 0) {
        int s = (lane < 16) ? wsum[lane] : 0;
#pragma unroll
        for (int o = 8; o; o >>= 1) s += __shfl_xor(s, o, 64);
        if (lane == 0) tsum[blockIdx.x] = s;
    }
}

__global__ __launch_bounds__(64) void scan_b(int* __restrict__ tsum,
                                             int* __restrict__ tbase, int NT,
                                             int* __restrict__ off, int N, int E) {
    if (threadIdx.x == 0) {
        int run = 0;
        for (int i = 0; i < NT; ++i) { tbase[i] = run; run += tsum[i]; }
        off[N] = E;
    }
}

__global__ __launch_bounds__(1024) void scan_c(const int* __restrict__ deg,
                                               const int* __restrict__ tbase,
                                               int* __restrict__ off, int N) {
    __shared__ int wsum[16];
    int t = blockIdx.x * 1024 + threadIdx.x;
    int lane = threadIdx.x & 63, wid = threadIdx.x >> 6;
    int v = (t < N) ? deg[t] : 0;
    int incl = v;
#pragma unroll
    for (int s = 1; s < 64; s <<= 1) {
        int tmp = __shfl_up(incl, s, 64);
        if (lane >= s) incl += tmp;
    }
    if (lane == 63) wsum[wid] = incl;
    __syncthreads();
    int woff = 0;
    for (int w = 0; w < wid; ++w) woff += wsum[w];
    if (t < N) off[t] = tbase[blockIdx.x] + woff + incl - v;
}

__global__ __launch_bounds__(256) void cursor_init(const int* __restrict__ off,
                                                   int* __restrict__ bcur) {
    int b = threadIdx.x;
    if (b < NB) bcur[b] = off[b * NPB];
}

// ---------------- pass 1: multisplit edges into dst-range buckets ----------------
// bpair[slot] = {src, dstLocal<<22 | eid}
__global__ __launch_bounds__(256) void bucket_fill(const int* __restrict__ src,
                                                   const int* __restrict__ dst,
                                                   int* __restrict__ bcur,
                                                   int2* __restrict__ bpair, int E) {
    __shared__ int hist[NB], cnt2[NB], gbase[NB];
    int tid = threadIdx.x;
    int base = blockIdx.x * TILE;
    for (int i = tid; i < NB; i += 256) { hist[i] = 0; cnt2[i] = 0; }
    __syncthreads();
    // phase A: histogram
    for (int i = 0; i < TILE / 256; ++i) {
        int e = base + i * 256 + tid;
        if (e < E) atomicAdd(&hist[dst[e] / NPB], 1);
    }
    __syncthreads();
    // reserve contiguous segment per bucket
    for (int b = tid; b < NB; b += 256)
        if (hist[b]) gbase[b] = atomicAdd(&bcur[b], hist[b]);
    __syncthreads();
    // phase B: scatter into private segments
    for (int i = 0; i < TILE / 256; ++i) {
        int e = base + i * 256 + tid;
        if (e < E) {
            int d = dst[e];
            int b = d / NPB;
            int lp = atomicAdd(&cnt2[b], 1);
            bpair[gbase[b] + lp] = make_int2(src[e], ((d - b * NPB) << 22) | e);
        }
    }
}

// ---------------- pass 2: within-bucket counting sort into final CSR ----------------
__global__ __launch_bounds__(256) void csr_scatter(const int* __restrict__ off,
                                                   const int2* __restrict__ bpair,
                                                   int2* __restrict__ pair, int N) {
    __shared__ int cur[NPB];
    int tid = threadIdx.x;
    int node0 = blockIdx.x * NPB;
    for (int i = tid; i < NPB; i += 256) cur[i] = off[node0 + i];
    __syncthreads();
    int beg = off[node0], end = off[node0 + NPB];
    for (int i = beg + tid; i < end; i += 256) {
        int2 p = bpair[i];
        int dl = (p.y >> 22) & 511;
        int eid = p.y & 0x3FFFFF;
        int pos = atomicAdd(&cur[dl], 1);
        pair[pos] = make_int2(p.x, eid);
    }
}

// ---------------- MFMA GEMM: out = A[N,K] @ W[K,COLS] (hi/lo split, fp32-accurate) ----
template<int K, int COLS, int MODE>
__global__ __launch_bounds__(256) void mfma_gemm(const float* __restrict__ A,
                                                 const float* __restrict__ W,
                                                 const float* __restrict__ dinv,
                                                 const float* __restrict__ bias,
                                                 u16* __restrict__ out_b,
                                                 float* __restrict__ out_f,
                                                 int N) {
    constexpr int KP = K + 8;
    constexpr int AP = 72;
    constexpr int NT = COLS / 16;
    __shared__ __align__(16) u16 Wh[COLS * KP];
    __shared__ __align__(16) u16 Wl[COLS * KP];
    __shared__ __align__(16) u16 Ah[64 * AP];
    __shared__ __align__(16) u16 Al[64 * AP];

    const int tid  = threadIdx.x;
    const int wave = tid >> 6;
    const int lane = tid & 63;
    const int lr   = lane & 15;
    const int kg   = lane >> 4;
    const int row0 = blockIdx.x * 64;

    for (int e = tid; e < K * COLS; e += 256) {
        int k = e / COLS, c = e % COLS;
        int gidx = (MODE == 2) ? (((c >> 6) * K + k) * 64 + (c & 63)) : e;
        float f = W[gidx];
        u16 hi = f2bf(f);
        u16 lo = f2bf(f - bf2f(hi));
        Wh[c * KP + k] = hi;
        Wl[c * KP + k] = lo;
    }

    f32x4 acc[NT];
#pragma unroll
    for (int c = 0; c < NT; ++c) acc[c] = (f32x4){0.f, 0.f, 0.f, 0.f};

    for (int kc = 0; kc < K; kc += 64) {
        __syncthreads();
#pragma unroll
        for (int it = 0; it < 4; ++it) {
            int idx = it * 256 + tid;
            int r  = idx >> 4;
            int k4 = (idx & 15) * 4;
            int gr = row0 + r;
            float4 v = make_float4(0.f, 0.f, 0.f, 0.f);
            if (gr < N) v = *(const float4*)(A + (size_t)gr * K + kc + k4);
            u16 h0 = f2bf(v.x), h1 = f2bf(v.y), h2 = f2bf(v.z), h3 = f2bf(v.w);
            ushort4 hv = make_ushort4(h0, h1, h2, h3);
            ushort4 lv = make_ushort4(f2bf(v.x - bf2f(h0)), f2bf(v.y - bf2f(h1)),
                                      f2bf(v.z - bf2f(h2)), f2bf(v.w - bf2f(h3)));
            *(ushort4*)(Ah + r * AP + k4) = hv;
            *(ushort4*)(Al + r * AP + k4) = lv;
        }
        __syncthreads();
#pragma unroll
        for (int ks = 0; ks < 64; ks += 32) {
            const int arow = wave * 16 + lr;
            bf16x8 ah = *(const bf16x8*)(Ah + arow * AP + ks + kg * 8);
            bf16x8 al = *(const bf16x8*)(Al + arow * AP + ks + kg * 8);
#pragma unroll
            for (int c = 0; c < NT; ++c) {
                const int wrow = c * 16 + lr;
                bf16x8 bh = *(const bf16x8*)(Wh + wrow * KP + kc + ks + kg * 8);
                bf16x8 bl = *(const bf16x8*)(Wl + wrow * KP + kc + ks + kg * 8);
                acc[c] = __builtin_amdgcn_mfma_f32_16x16x32_bf16(ah, bh, acc[c], 0, 0, 0);
                acc[c] = __builtin_amdgcn_mfma_f32_16x16x32_bf16(ah, bl, acc[c], 0, 0, 0);
                acc[c] = __builtin_amdgcn_mfma_f32_16x16x32_bf16(al, bh, acc[c], 0, 0, 0);
            }
        }
    }

#pragma unroll
    for (int rr = 0; rr < 4; ++rr) {
        int n = row0 + wave * 16 + kg * 4 + rr;
        if (n >= N) continue;
        float dv = (MODE == 0) ? dinv[n] : 1.f;
#pragma unroll
        for (int c = 0; c < NT; ++c) {
            int col = c * 16 + lr;
            float v = acc[c][rr];
            if (MODE == 0) {
                out_b[(size_t)n * 64 + col] = f2bf(v * dv);
            } else {
                if (col < 64) out_b[(size_t)n * 64 + col] = f2bf(v);
                else out_f[(size_t)n * 64 + (col - 64)] = v + bias[col - 64];
            }
        }
    }
}

// ---------------- gather: h[v] = relu?( dinv[v]*(sum_in ts[s] + ts[v]) + bias ) ----------------
// packed: 2 bf16 features per lane (u32), half-wave per edge, 2 edges per pass
__global__ __launch_bounds__(256) void gather_kernel(const int* __restrict__ off,
                                                     const int2* __restrict__ pair,
                                                     const u16* __restrict__ ts,
                                                     const float* __restrict__ dinv,
                                                     const float* __restrict__ bias,
                                                     float* __restrict__ outh, int N,
                                                     int do_relu) {
    long tid = (long)blockIdx.x * blockDim.x + threadIdx.x;
    int v = (int)(tid >> 6), j = (int)(tid & 63);
    if (v >= N) return;
    int l = j & 31, hh = j >> 5;
    const u32* tsw = (const u32*)ts;  // row stride 32 u32
    float ax = 0.f, ay = 0.f;
    int beg = off[v], end = off[v + 1];
    for (int i0 = beg; i0 < end; i0 += 64) {
        int idx = i0 + j;
        int sj = (idx < end) ? pair[idx].x : 0;
        int m = end - i0;
        if (m > 64) m = 64;
        for (int k = 0; k < m; k += 2) {
            int kk = k + hh;
            int s = __shfl(sj, kk, 64);
            if (kk < m) {
                u32 u = tsw[(size_t)s * 32 + l];
                ax += __uint_as_float(u << 16);
                ay += __uint_as_float(u & 0xffff0000u);
            }
        }
    }
    // combine half-wave partial sums
    ax += __shfl_xor(ax, 32, 64);
    ay += __shfl_xor(ay, 32, 64);
    // self-loop term
    u32 su = tsw[(size_t)v * 32 + l];
    ax += __uint_as_float(su << 16);
    ay += __uint_as_float(su & 0xffff0000u);
    float dv = dinv[v];
    float2 b2 = *(const float2*)(bias + 2 * l);
    float vx = ax * dv + b2.x;
    float vy = ay * dv + b2.y;
    if (do_relu) { vx = fmaxf(vx, 0.f); vy = fmaxf(vy, 0.f); }
    if (hh == 0) *(float2*)(outh + (size_t)v * HID + 2 * l) = make_float2(vx, vy);
}

// ---------------- node-centric decode ----------------
__global__ __launch_bounds__(256) void decode_kernel(const int* __restrict__ off,
                                                     const int2* __restrict__ pair,
                                                     const u16* __restrict__ a,
                                                     const float* __restrict__ c,
                                                     const float* __restrict__ Wl2,
                                                     const float* __restrict__ bl2,
                                                     float* __restrict__ out, int N) {
    long tid = (long)blockIdx.x * blockDim.x + threadIdx.x;
    int v = (int)(tid >> 6), j = (int)(tid & 63);
    if (v >= N) return;
    int l = j & 31, h = j >> 5;
    float2 c2 = *(const float2*)(c + (size_t)v * HID + 2 * l);
    float2 w2 = *(const float2*)(Wl2 + 2 * l);
    float bl2v = bl2[0];
    int beg = off[v], end = off[v + 1];
    for (int i0 = beg; i0 < end; i0 += 64) {
        int idx = i0 + j;
        int2 pr = (idx < end) ? pair[idx] : make_int2(0, 0);
        int m = end - i0;
        if (m > 64) m = 64;
        for (int k = 0; k < m; k += 2) {
            int kk = k + h;
            int s   = __shfl(pr.x, kk, 64);
            int eid = __shfl(pr.y, kk, 64);
            bool act = kk < m;
            float p = 0.f;
            if (act) {
                u32 u = *(const u32*)(a + (size_t)s * HID + 2 * l);
                float f0 = __uint_as_float(u << 16);
                float f1 = __uint_as_float(u & 0xffff0000u);
                p = fmaxf(f0 + c2.x, 0.f) * w2.x + fmaxf(f1 + c2.y, 0.f) * w2.y;
            }
#pragma unroll
            for (int o = 16; o; o >>= 1) p += __shfl_xor(p, o, 64);
            if (act && l == 0) out[eid] = 1.f / (1.f + expf(-(p + bl2v)));
        }
    }
}

extern "C" void kernel_launch(void* const* d_in, const int* in_sizes, int n_in,
                              void* d_out, int out_size, void* d_ws, size_t ws_size,
                              hipStream_t stream) {
    const float* x   = (const float*)d_in[0];
    const int*   ei  = (const int*)d_in[1];
    const float* W1  = (const float*)d_in[2];
    const float* b1  = (const float*)d_in[3];
    const float* W2  = (const float*)d_in[4];
    const float* b2  = (const float*)d_in[5];
    const float* Wl1 = (const float*)d_in[6];
    const float* bl1 = (const float*)d_in[7];
    const float* Wl2 = (const float*)d_in[8];
    const float* bl2 = (const float*)d_in[9];
    float* out = (float*)d_out;

    const int N = in_sizes[0] / IN_DIM;   // 100000
    const int E = in_sizes[1] / 2;        // 3200000
    const int* src = ei;
    const int* dst = ei + E;

    // workspace layout
    char* ws = (char*)d_ws;
    int*   deg   = (int*)ws;    ws += (size_t)(N + 64) * 4;
    int*   off   = (int*)ws;    ws += (size_t)(N + 64) * 4;
    float* dinv  = (float*)ws;  ws += (size_t)(N + 64) * 4;
    int*   bcur  = (int*)ws;    ws += 1024;
    int*   tsum  = (int*)ws;    ws += 1024;
    int*   tbase = (int*)ws;    ws += 1024;
    int2*  pair  = (int2*)ws;   ws += (size_t)E * 8;
    u16*   tb    = (u16*)ws;    ws += (size_t)N * HID * 2;   // t1, t2, then a (bf16)
    float* h     = (float*)ws;  ws += (size_t)N * HID * 4;   // h, then z
    float* c     = (float*)ws;  ws += (size_t)N * HID * 4;
    int2*  bpair = (int2*)h;    // overlay: E*8 == N*HID*4, dead before gather1

    const int TPB = 256;
    long nodeT = (long)N * HID;
    int nodeBlocks = (int)((nodeT + TPB - 1) / TPB);
    int eBlocks = (E + TPB - 1) / TPB;
    int nBlocks = (N + TPB - 1) / TPB;
    int gBlocks = (N + 63) / 64;
    int NT = (N + 1023) / 1024;

    // ---- degrees + norm ----
    hipMemsetAsync(deg, 0, (size_t)N * sizeof(int), stream);
    deg_kernel<<<eBlocks, TPB, 0, stream>>>(dst, E, deg);
    dinv_kernel<<<nBlocks, TPB, 0, stream>>>(deg, dinv, N);

    // ---- hierarchical scan deg -> off ----
    scan_a<<<NT, 1024, 0, stream>>>(deg, tsum, N);
    scan_b<<<1, 64, 0, stream>>>(tsum, tbase, NT, off, N, E);
    scan_c<<<NT, 1024, 0, stream>>>(deg, tbase, off, N);

    // ---- bucketed CSR build ----
    cursor_init<<<1, TPB, 0, stream>>>(off, bcur);
    bucket_fill<<<(E + TILE - 1) / TILE, TPB, 0, stream>>>(src, dst, bcur, bpair, E);
    csr_scatter<<<NB, TPB, 0, stream>>>(off, bpair, pair, N);

    // ---- conv1: t1 = bf16((x@W1)*dinv) ; h = relu(gather + b1) ----
    mfma_gemm<IN_DIM, 64, 0><<<gBlocks, TPB, 0, stream>>>(x, W1, dinv, nullptr, tb, nullptr, N);
    gather_kernel<<<nodeBlocks, TPB, 0, stream>>>(off, pair, tb, dinv, b1, h, N, 1);

    // ---- conv2: t2 = bf16((h@W2)*dinv) ; z = gather + b2 (into h) ----
    mfma_gemm<HID, 64, 0><<<gBlocks, TPB, 0, stream>>>(h, W2, dinv, nullptr, tb, nullptr, N);
    gather_kernel<<<nodeBlocks, TPB, 0, stream>>>(off, pair, tb, dinv, b2, h, N, 0);

    // ---- decoder precompute: a = bf16(z@Wl1_top) into tb, c = z@Wl1_bot + bl1 ----
    mfma_gemm<HID, 128, 2><<<gBlocks, TPB, 0, stream>>>(h, Wl1, nullptr, bl1, tb, c, N);

    // ---- node-centric decode ----
    decode_kernel<<<nodeBlocks, TPB, 0, stream>>>(off, pair, tb, c, Wl2, bl2, out, N);
}

// Round 6
// 602.249 us; speedup vs baseline: 4.3821x; 1.3040x over previous
//
#include <hip/hip_runtime.h>
#include <hip/hip_bf16.h>
#include <math.h>

#define HID 64
#define IN_DIM 256
#define NPB 400          // nodes per bucket
#define NB  250          // buckets (N/NPB)
#define TILE 8192        // edges per tile block

typedef unsigned short u16;
typedef unsigned int u32;

using bf16x8 = __attribute__((ext_vector_type(8))) short;
using f32x4  = __attribute__((ext_vector_type(4))) float;

__device__ __forceinline__ float bf2f(u16 v) {
    return __uint_as_float((u32)v << 16);
}
__device__ __forceinline__ u16 f2bf(float f) {
    __hip_bfloat16 b = __float2bfloat16(f);  // RNE
    return *(u16*)&b;
}

// ---------------- pass 0: bucket histogram ----------------
__global__ __launch_bounds__(256) void bucket_hist(const int* __restrict__ dst, int E,
                                                   int* __restrict__ bhist) {
    __shared__ int hist[NB];
    int tid = threadIdx.x;
    int base = blockIdx.x * TILE;
    for (int i = tid; i < NB; i += 256) hist[i] = 0;
    __syncthreads();
    for (int i = 0; i < TILE / 256; ++i) {
        int e = base + i * 256 + tid;
        if (e < E) atomicAdd(&hist[dst[e] / NPB], 1);
    }
    __syncthreads();
    for (int b = tid; b < NB; b += 256)
        if (hist[b]) atomicAdd(&bhist[b], hist[b]);
}

// ---------------- bucket scan (1 block) ----------------
__global__ __launch_bounds__(64) void bscan(const int* __restrict__ bhist,
                                            int* __restrict__ bbase,
                                            int* __restrict__ bcur,
                                            int* __restrict__ off, int N, int E) {
    if (threadIdx.x == 0) {
        int run = 0;
        for (int b = 0; b < NB; ++b) {
            bbase[b] = run;
            bcur[b] = run;
            run += bhist[b];
        }
        bbase[NB] = run;
        off[N] = E;
    }
}

// ---------------- pass 1: multisplit edges into dst-range buckets ----------------
// bpair[slot] = {src, dstLocal<<22 | eid}
__global__ __launch_bounds__(256) void bucket_fill(const int* __restrict__ src,
                                                   const int* __restrict__ dst,
                                                   int* __restrict__ bcur,
                                                   int2* __restrict__ bpair, int E) {
    __shared__ int hist[NB], cnt2[NB], gbase[NB];
    int tid = threadIdx.x;
    int base = blockIdx.x * TILE;
    for (int i = tid; i < NB; i += 256) { hist[i] = 0; cnt2[i] = 0; }
    __syncthreads();
    for (int i = 0; i < TILE / 256; ++i) {
        int e = base + i * 256 + tid;
        if (e < E) atomicAdd(&hist[dst[e] / NPB], 1);
    }
    __syncthreads();
    for (int b = tid; b < NB; b += 256)
        if (hist[b]) gbase[b] = atomicAdd(&bcur[b], hist[b]);
    __syncthreads();
    for (int i = 0; i < TILE / 256; ++i) {
        int e = base + i * 256 + tid;
        if (e < E) {
            int d = dst[e];
            int b = d / NPB;
            int lp = atomicAdd(&cnt2[b], 1);
            bpair[gbase[b] + lp] = make_int2(src[e], ((d - b * NPB) << 22) | e);
        }
    }
}

// ---------------- pass 2: within-bucket counting sort -> CSR + off + dinv ----------------
__global__ __launch_bounds__(256) void csr_scatter(const int* __restrict__ bbase,
                                                   const int2* __restrict__ bpair,
                                                   int* __restrict__ csr_src,
                                                   int* __restrict__ csr_eid,
                                                   int* __restrict__ off,
                                                   float* __restrict__ dinv, int N) {
    __shared__ int cnt[NPB];
    __shared__ int cur[NPB];
    int tid = threadIdx.x;
    int b = blockIdx.x;
    int node0 = b * NPB;
    int beg = bbase[b], end = bbase[b + 1];
    for (int i = tid; i < NPB; i += 256) cnt[i] = 0;
    __syncthreads();
    for (int i = beg + tid; i < end; i += 256)
        atomicAdd(&cnt[(bpair[i].y >> 22) & 511], 1);
    __syncthreads();
    // wave 0: exclusive scan of cnt -> cur (base = beg)
    if (tid < 64) {
        int lane = tid;
        int carry = beg;
#pragma unroll
        for (int c0 = 0; c0 < NPB; c0 += 64) {
            int v = cnt[c0 + lane];
            int incl = v;
#pragma unroll
            for (int s = 1; s < 64; s <<= 1) {
                int t = __shfl_up(incl, s, 64);
                if (lane >= s) incl += t;
            }
            cur[c0 + lane] = carry + incl - v;
            carry += __shfl(incl, 63, 64);
        }
    }
    __syncthreads();
    for (int i = tid; i < NPB; i += 256) {
        off[node0 + i] = cur[i];
        dinv[node0 + i] = rsqrtf((float)cnt[i] + 1.0f);
    }
    __syncthreads();
    for (int i = beg + tid; i < end; i += 256) {
        int2 p = bpair[i];
        int dl = (p.y >> 22) & 511;
        int pos = atomicAdd(&cur[dl], 1);
        csr_src[pos] = p.x;
        csr_eid[pos] = p.y & 0x3FFFFF;
    }
}

// ---------------- MFMA GEMM: out = A[N,K] @ W[K,COLS] (hi/lo split, fp32-accurate) ----
template<int K, int COLS, int MODE>
__global__ __launch_bounds__(256) void mfma_gemm(const float* __restrict__ A,
                                                 const float* __restrict__ W,
                                                 const float* __restrict__ dinv,
                                                 const float* __restrict__ bias,
                                                 u16* __restrict__ out_b,
                                                 float* __restrict__ out_f,
                                                 int N) {
    constexpr int KP = K + 8;
    constexpr int AP = 72;
    constexpr int NT = COLS / 16;
    __shared__ __align__(16) u16 Wh[COLS * KP];
    __shared__ __align__(16) u16 Wl[COLS * KP];
    __shared__ __align__(16) u16 Ah[64 * AP];
    __shared__ __align__(16) u16 Al[64 * AP];

    const int tid  = threadIdx.x;
    const int wave = tid >> 6;
    const int lane = tid & 63;
    const int lr   = lane & 15;
    const int kg   = lane >> 4;
    const int row0 = blockIdx.x * 64;

    for (int e = tid; e < K * COLS; e += 256) {
        int k = e / COLS, c = e % COLS;
        int gidx = (MODE == 2) ? (((c >> 6) * K + k) * 64 + (c & 63)) : e;
        float f = W[gidx];
        u16 hi = f2bf(f);
        u16 lo = f2bf(f - bf2f(hi));
        Wh[c * KP + k] = hi;
        Wl[c * KP + k] = lo;
    }

    f32x4 acc[NT];
#pragma unroll
    for (int c = 0; c < NT; ++c) acc[c] = (f32x4){0.f, 0.f, 0.f, 0.f};

    for (int kc = 0; kc < K; kc += 64) {
        __syncthreads();
#pragma unroll
        for (int it = 0; it < 4; ++it) {
            int idx = it * 256 + tid;
            int r  = idx >> 4;
            int k4 = (idx & 15) * 4;
            int gr = row0 + r;
            float4 v = make_float4(0.f, 0.f, 0.f, 0.f);
            if (gr < N) v = *(const float4*)(A + (size_t)gr * K + kc + k4);
            u16 h0 = f2bf(v.x), h1 = f2bf(v.y), h2 = f2bf(v.z), h3 = f2bf(v.w);
            ushort4 hv = make_ushort4(h0, h1, h2, h3);
            ushort4 lv = make_ushort4(f2bf(v.x - bf2f(h0)), f2bf(v.y - bf2f(h1)),
                                      f2bf(v.z - bf2f(h2)), f2bf(v.w - bf2f(h3)));
            *(ushort4*)(Ah + r * AP + k4) = hv;
            *(ushort4*)(Al + r * AP + k4) = lv;
        }
        __syncthreads();
#pragma unroll
        for (int ks = 0; ks < 64; ks += 32) {
            const int arow = wave * 16 + lr;
            bf16x8 ah = *(const bf16x8*)(Ah + arow * AP + ks + kg * 8);
            bf16x8 al = *(const bf16x8*)(Al + arow * AP + ks + kg * 8);
#pragma unroll
            for (int c = 0; c < NT; ++c) {
                const int wrow = c * 16 + lr;
                bf16x8 bh = *(const bf16x8*)(Wh + wrow * KP + kc + ks + kg * 8);
                bf16x8 bl = *(const bf16x8*)(Wl + wrow * KP + kc + ks + kg * 8);
                acc[c] = __builtin_amdgcn_mfma_f32_16x16x32_bf16(ah, bh, acc[c], 0, 0, 0);
                acc[c] = __builtin_amdgcn_mfma_f32_16x16x32_bf16(ah, bl, acc[c], 0, 0, 0);
                acc[c] = __builtin_amdgcn_mfma_f32_16x16x32_bf16(al, bh, acc[c], 0, 0, 0);
            }
        }
    }

#pragma unroll
    for (int rr = 0; rr < 4; ++rr) {
        int n = row0 + wave * 16 + kg * 4 + rr;
        if (n >= N) continue;
        float dv = (MODE == 0) ? dinv[n] : 1.f;
#pragma unroll
        for (int c = 0; c < NT; ++c) {
            int col = c * 16 + lr;
            float v = acc[c][rr];
            if (MODE == 0) {
                out_b[(size_t)n * 64 + col] = f2bf(v * dv);
            } else {
                if (col < 64) out_b[(size_t)n * 64 + col] = f2bf(v);
                else out_f[(size_t)n * 64 + (col - 64)] = v + bias[col - 64];
            }
        }
    }
}

// ---------------- gather: 4 edges/pass, 4 features/lane ----------------
// h[v] = relu?( dinv[v]*(sum_in ts[s] + ts[v]) + bias )
__global__ __launch_bounds__(256) void gather_kernel(const int* __restrict__ off,
                                                     const int* __restrict__ csr_src,
                                                     const u16* __restrict__ ts,
                                                     const float* __restrict__ dinv,
                                                     const float* __restrict__ bias,
                                                     float* __restrict__ outh, int N,
                                                     int do_relu) {
    long tid = (long)blockIdx.x * blockDim.x + threadIdx.x;
    int v = (int)(tid >> 6), j = (int)(tid & 63);
    if (v >= N) return;
    int l = j & 15, g = j >> 4;
    float a0 = 0.f, a1 = 0.f, a2 = 0.f, a3 = 0.f;
    int beg = off[v], end = off[v + 1];
    for (int k = beg + g; k < end; k += 4) {
        int s = csr_src[k];
        uint2 u = *(const uint2*)(ts + (size_t)s * HID + 4 * l);
        a0 += __uint_as_float(u.x << 16);
        a1 += __uint_as_float(u.x & 0xffff0000u);
        a2 += __uint_as_float(u.y << 16);
        a3 += __uint_as_float(u.y & 0xffff0000u);
    }
    // combine the 4 groups
#pragma unroll
    for (int o = 16; o < 64; o <<= 1) {
        a0 += __shfl_xor(a0, o, 64);
        a1 += __shfl_xor(a1, o, 64);
        a2 += __shfl_xor(a2, o, 64);
        a3 += __shfl_xor(a3, o, 64);
    }
    // self-loop term
    uint2 su = *(const uint2*)(ts + (size_t)v * HID + 4 * l);
    a0 += __uint_as_float(su.x << 16);
    a1 += __uint_as_float(su.x & 0xffff0000u);
    a2 += __uint_as_float(su.y << 16);
    a3 += __uint_as_float(su.y & 0xffff0000u);
    float dv = dinv[v];
    float4 b4 = *(const float4*)(bias + 4 * l);
    float4 r;
    r.x = a0 * dv + b4.x;
    r.y = a1 * dv + b4.y;
    r.z = a2 * dv + b4.z;
    r.w = a3 * dv + b4.w;
    if (do_relu) {
        r.x = fmaxf(r.x, 0.f); r.y = fmaxf(r.y, 0.f);
        r.z = fmaxf(r.z, 0.f); r.w = fmaxf(r.w, 0.f);
    }
    if (g == 0) *(float4*)(outh + (size_t)v * HID + 4 * l) = r;
}

// ---------------- node-centric decode: 4 edges/pass, 4 features/lane ----------------
__global__ __launch_bounds__(256) void decode_kernel(const int* __restrict__ off,
                                                     const int* __restrict__ csr_src,
                                                     const int* __restrict__ csr_eid,
                                                     const u16* __restrict__ a,
                                                     const float* __restrict__ c,
                                                     const float* __restrict__ Wl2,
                                                     const float* __restrict__ bl2,
                                                     float* __restrict__ out, int N) {
    long tid = (long)blockIdx.x * blockDim.x + threadIdx.x;
    int v = (int)(tid >> 6), j = (int)(tid & 63);
    if (v >= N) return;
    int l = j & 15, g = j >> 4;
    float4 c4 = *(const float4*)(c + (size_t)v * HID + 4 * l);
    float4 w4 = *(const float4*)(Wl2 + 4 * l);
    float bl2v = bl2[0];
    int beg = off[v], end = off[v + 1];
    for (int k = beg + g; ; k += 4) {
        bool act = k < end;
        if (!__any(act)) break;
        float p = 0.f;
        int eid = 0;
        if (act) {
            int s = csr_src[k];
            eid = csr_eid[k];
            uint2 u = *(const uint2*)(a + (size_t)s * HID + 4 * l);
            float f0 = __uint_as_float(u.x << 16);
            float f1 = __uint_as_float(u.x & 0xffff0000u);
            float f2 = __uint_as_float(u.y << 16);
            float f3 = __uint_as_float(u.y & 0xffff0000u);
            p = fmaxf(f0 + c4.x, 0.f) * w4.x + fmaxf(f1 + c4.y, 0.f) * w4.y +
                fmaxf(f2 + c4.z, 0.f) * w4.z + fmaxf(f3 + c4.w, 0.f) * w4.w;
        }
#pragma unroll
        for (int o = 1; o < 16; o <<= 1) p += __shfl_xor(p, o, 64);
        if (act && l == 0) {
            float s = 1.f / (1.f + expf(-(p + bl2v)));
            __builtin_nontemporal_store(s, &out[eid]);
        }
    }
}

extern "C" void kernel_launch(void* const* d_in, const int* in_sizes, int n_in,
                              void* d_out, int out_size, void* d_ws, size_t ws_size,
                              hipStream_t stream) {
    const float* x   = (const float*)d_in[0];
    const int*   ei  = (const int*)d_in[1];
    const float* W1  = (const float*)d_in[2];
    const float* b1  = (const float*)d_in[3];
    const float* W2  = (const float*)d_in[4];
    const float* b2  = (const float*)d_in[5];
    const float* Wl1 = (const float*)d_in[6];
    const float* bl1 = (const float*)d_in[7];
    const float* Wl2 = (const float*)d_in[8];
    const float* bl2 = (const float*)d_in[9];
    float* out = (float*)d_out;

    const int N = in_sizes[0] / IN_DIM;   // 100000
    const int E = in_sizes[1] / 2;        // 3200000
    const int* src = ei;
    const int* dst = ei + E;

    // workspace layout
    char* ws = (char*)d_ws;
    int*   off     = (int*)ws;    ws += (size_t)(N + 64) * 4;
    float* dinv    = (float*)ws;  ws += (size_t)(N + 64) * 4;
    int*   bhist   = (int*)ws;    ws += 1024;
    int*   bbase   = (int*)ws;    ws += 1024 + 64;
    int*   bcur    = (int*)ws;    ws += 1024;
    int*   csr_src = (int*)ws;    ws += (size_t)E * 4;
    int*   csr_eid = (int*)ws;    ws += (size_t)E * 4;
    u16*   tb      = (u16*)ws;    ws += (size_t)N * HID * 2;   // t1, t2, then a (bf16)
    float* h       = (float*)ws;  ws += (size_t)N * HID * 4;   // h, then z
    float* c       = (float*)ws;  ws += (size_t)N * HID * 4;
    int2*  bpair   = (int2*)h;    // overlay: E*8 == N*HID*4, dead before gather1

    const int TPB = 256;
    long nodeT = (long)N * HID;
    int nodeBlocks = (int)((nodeT + TPB - 1) / TPB);
    int tBlocks = (E + TILE - 1) / TILE;
    int gBlocks = (N + 63) / 64;

    // ---- CSR build ----
    hipMemsetAsync(bhist, 0, NB * sizeof(int), stream);
    bucket_hist<<<tBlocks, TPB, 0, stream>>>(dst, E, bhist);
    bscan<<<1, 64, 0, stream>>>(bhist, bbase, bcur, off, N, E);
    bucket_fill<<<tBlocks, TPB, 0, stream>>>(src, dst, bcur, bpair, E);
    csr_scatter<<<NB, TPB, 0, stream>>>(bbase, bpair, csr_src, csr_eid, off, dinv, N);

    // ---- conv1: t1 = bf16((x@W1)*dinv) ; h = relu(gather + b1) ----
    mfma_gemm<IN_DIM, 64, 0><<<gBlocks, TPB, 0, stream>>>(x, W1, dinv, nullptr, tb, nullptr, N);
    gather_kernel<<<nodeBlocks, TPB, 0, stream>>>(off, csr_src, tb, dinv, b1, h, N, 1);

    // ---- conv2: t2 = bf16((h@W2)*dinv) ; z = gather + b2 (into h) ----
    mfma_gemm<HID, 64, 0><<<gBlocks, TPB, 0, stream>>>(h, W2, dinv, nullptr, tb, nullptr, N);
    gather_kernel<<<nodeBlocks, TPB, 0, stream>>>(off, csr_src, tb, dinv, b2, h, N, 0);

    // ---- decoder precompute: a = bf16(z@Wl1_top) into tb, c = z@Wl1_bot + bl1 ----
    mfma_gemm<HID, 128, 2><<<gBlocks, TPB, 0, stream>>>(h, Wl1, nullptr, bl1, tb, c, N);

    // ---- node-centric decode ----
    decode_kernel<<<nodeBlocks, TPB, 0, stream>>>(off, csr_src, csr_eid, tb, c, Wl2, bl2, out, N);
}

// Round 7
// 584.075 us; speedup vs baseline: 4.5185x; 1.0311x over previous
//
#include <hip/hip_runtime.h>
#include <hip/hip_bf16.h>
#include <math.h>

#define HID 64
#define IN_DIM 256
#define NPB 400          // nodes per bucket
#define NB  250          // buckets (N/NPB)
#define TILE 8192        // edges per tile block

typedef unsigned short u16;
typedef unsigned int u32;

using bf16x8 = __attribute__((ext_vector_type(8))) short;
using f32x4  = __attribute__((ext_vector_type(4))) float;

__device__ __forceinline__ float bf2f(u16 v) {
    return __uint_as_float((u32)v << 16);
}
__device__ __forceinline__ u16 f2bf(float f) {
    __hip_bfloat16 b = __float2bfloat16(f);  // RNE
    return *(u16*)&b;
}

// ---------------- pass 0: bucket histogram ----------------
__global__ __launch_bounds__(256) void bucket_hist(const int* __restrict__ dst, int E,
                                                   int* __restrict__ bhist) {
    __shared__ int hist[NB];
    int tid = threadIdx.x;
    int base = blockIdx.x * TILE;
    for (int i = tid; i < NB; i += 256) hist[i] = 0;
    __syncthreads();
    for (int i = 0; i < TILE / 256; ++i) {
        int e = base + i * 256 + tid;
        if (e < E) atomicAdd(&hist[dst[e] / NPB], 1);
    }
    __syncthreads();
    for (int b = tid; b < NB; b += 256)
        if (hist[b]) atomicAdd(&bhist[b], hist[b]);
}

// ---------------- bucket scan (1 block) ----------------
__global__ __launch_bounds__(64) void bscan(const int* __restrict__ bhist,
                                            int* __restrict__ bbase,
                                            int* __restrict__ bcur,
                                            int* __restrict__ off, int N, int E) {
    if (threadIdx.x == 0) {
        int run = 0;
        for (int b = 0; b < NB; ++b) {
            bbase[b] = run;
            bcur[b] = run;
            run += bhist[b];
        }
        bbase[NB] = run;
        off[N] = E;
    }
}

// ---------------- pass 1: multisplit edges into dst-range buckets ----------------
// bpair[slot] = {src, dstLocal<<22 | eid}
__global__ __launch_bounds__(256) void bucket_fill(const int* __restrict__ src,
                                                   const int* __restrict__ dst,
                                                   int* __restrict__ bcur,
                                                   int2* __restrict__ bpair, int E) {
    __shared__ int hist[NB], cnt2[NB], gbase[NB];
    int tid = threadIdx.x;
    int base = blockIdx.x * TILE;
    for (int i = tid; i < NB; i += 256) { hist[i] = 0; cnt2[i] = 0; }
    __syncthreads();
    for (int i = 0; i < TILE / 256; ++i) {
        int e = base + i * 256 + tid;
        if (e < E) atomicAdd(&hist[dst[e] / NPB], 1);
    }
    __syncthreads();
    for (int b = tid; b < NB; b += 256)
        if (hist[b]) gbase[b] = atomicAdd(&bcur[b], hist[b]);
    __syncthreads();
    for (int i = 0; i < TILE / 256; ++i) {
        int e = base + i * 256 + tid;
        if (e < E) {
            int d = dst[e];
            int b = d / NPB;
            int lp = atomicAdd(&cnt2[b], 1);
            bpair[gbase[b] + lp] = make_int2(src[e], ((d - b * NPB) << 22) | e);
        }
    }
}

// ---------------- pass 2: within-bucket counting sort -> CSR + off + dinv ----------------
__global__ __launch_bounds__(256) void csr_scatter(const int* __restrict__ bbase,
                                                   const int2* __restrict__ bpair,
                                                   int* __restrict__ csr_src,
                                                   int* __restrict__ csr_eid,
                                                   int* __restrict__ off,
                                                   float* __restrict__ dinv, int N) {
    __shared__ int cnt[NPB];
    __shared__ int cur[NPB];
    int tid = threadIdx.x;
    int b = blockIdx.x;
    int node0 = b * NPB;
    int beg = bbase[b], end = bbase[b + 1];
    for (int i = tid; i < NPB; i += 256) cnt[i] = 0;
    __syncthreads();
    for (int i = beg + tid; i < end; i += 256)
        atomicAdd(&cnt[(bpair[i].y >> 22) & 511], 1);
    __syncthreads();
    // wave 0: exclusive scan of cnt -> cur (base = beg)
    if (tid < 64) {
        int lane = tid;
        int carry = beg;
#pragma unroll
        for (int c0 = 0; c0 < NPB; c0 += 64) {
            int v = cnt[c0 + lane];
            int incl = v;
#pragma unroll
            for (int s = 1; s < 64; s <<= 1) {
                int t = __shfl_up(incl, s, 64);
                if (lane >= s) incl += t;
            }
            cur[c0 + lane] = carry + incl - v;
            carry += __shfl(incl, 63, 64);
        }
    }
    __syncthreads();
    for (int i = tid; i < NPB; i += 256) {
        off[node0 + i] = cur[i];
        dinv[node0 + i] = rsqrtf((float)cnt[i] + 1.0f);
    }
    __syncthreads();
    for (int i = beg + tid; i < end; i += 256) {
        int2 p = bpair[i];
        int dl = (p.y >> 22) & 511;
        int pos = atomicAdd(&cur[dl], 1);
        csr_src[pos] = p.x;
        csr_eid[pos] = p.y & 0x3FFFFF;
    }
}

// ---------------- MFMA GEMM: out = A[N,K] @ W[K,COLS] (hi/lo split, fp32-accurate) ----
template<int K, int COLS, int MODE>
__global__ __launch_bounds__(256) void mfma_gemm(const float* __restrict__ A,
                                                 const float* __restrict__ W,
                                                 const float* __restrict__ dinv,
                                                 const float* __restrict__ bias,
                                                 u16* __restrict__ out_b,
                                                 float* __restrict__ out_f,
                                                 int N) {
    constexpr int KP = K + 8;
    constexpr int AP = 72;
    constexpr int NT = COLS / 16;
    __shared__ __align__(16) u16 Wh[COLS * KP];
    __shared__ __align__(16) u16 Wl[COLS * KP];
    __shared__ __align__(16) u16 Ah[64 * AP];
    __shared__ __align__(16) u16 Al[64 * AP];

    const int tid  = threadIdx.x;
    const int wave = tid >> 6;
    const int lane = tid & 63;
    const int lr   = lane & 15;
    const int kg   = lane >> 4;
    const int row0 = blockIdx.x * 64;

    for (int e = tid; e < K * COLS; e += 256) {
        int k = e / COLS, c = e % COLS;
        int gidx = (MODE == 2) ? (((c >> 6) * K + k) * 64 + (c & 63)) : e;
        float f = W[gidx];
        u16 hi = f2bf(f);
        u16 lo = f2bf(f - bf2f(hi));
        Wh[c * KP + k] = hi;
        Wl[c * KP + k] = lo;
    }

    f32x4 acc[NT];
#pragma unroll
    for (int c = 0; c < NT; ++c) acc[c] = (f32x4){0.f, 0.f, 0.f, 0.f};

    for (int kc = 0; kc < K; kc += 64) {
        __syncthreads();
#pragma unroll
        for (int it = 0; it < 4; ++it) {
            int idx = it * 256 + tid;
            int r  = idx >> 4;
            int k4 = (idx & 15) * 4;
            int gr = row0 + r;
            float4 v = make_float4(0.f, 0.f, 0.f, 0.f);
            if (gr < N) v = *(const float4*)(A + (size_t)gr * K + kc + k4);
            u16 h0 = f2bf(v.x), h1 = f2bf(v.y), h2 = f2bf(v.z), h3 = f2bf(v.w);
            ushort4 hv = make_ushort4(h0, h1, h2, h3);
            ushort4 lv = make_ushort4(f2bf(v.x - bf2f(h0)), f2bf(v.y - bf2f(h1)),
                                      f2bf(v.z - bf2f(h2)), f2bf(v.w - bf2f(h3)));
            *(ushort4*)(Ah + r * AP + k4) = hv;
            *(ushort4*)(Al + r * AP + k4) = lv;
        }
        __syncthreads();
#pragma unroll
        for (int ks = 0; ks < 64; ks += 32) {
            const int arow = wave * 16 + lr;
            bf16x8 ah = *(const bf16x8*)(Ah + arow * AP + ks + kg * 8);
            bf16x8 al = *(const bf16x8*)(Al + arow * AP + ks + kg * 8);
#pragma unroll
            for (int c = 0; c < NT; ++c) {
                const int wrow = c * 16 + lr;
                bf16x8 bh = *(const bf16x8*)(Wh + wrow * KP + kc + ks + kg * 8);
                bf16x8 bl = *(const bf16x8*)(Wl + wrow * KP + kc + ks + kg * 8);
                acc[c] = __builtin_amdgcn_mfma_f32_16x16x32_bf16(ah, bh, acc[c], 0, 0, 0);
                acc[c] = __builtin_amdgcn_mfma_f32_16x16x32_bf16(ah, bl, acc[c], 0, 0, 0);
                acc[c] = __builtin_amdgcn_mfma_f32_16x16x32_bf16(al, bh, acc[c], 0, 0, 0);
            }
        }
    }

#pragma unroll
    for (int rr = 0; rr < 4; ++rr) {
        int n = row0 + wave * 16 + kg * 4 + rr;
        if (n >= N) continue;
        float dv = (MODE == 0) ? dinv[n] : 1.f;
#pragma unroll
        for (int c = 0; c < NT; ++c) {
            int col = c * 16 + lr;
            float v = acc[c][rr];
            if (MODE == 0) {
                out_b[(size_t)n * 64 + col] = f2bf(v * dv);
            } else {
                if (col < 64) out_b[(size_t)n * 64 + col] = f2bf(v);
                else out_f[(size_t)n * 64 + (col - 64)] = v + bias[col - 64];
            }
        }
    }
}

// ---------------- gather: 8 edges/pass, 8 features/lane (uint4) ----------------
// h[v] = relu?( dinv[v]*(sum_in ts[s] + ts[v]) + bias )
__global__ __launch_bounds__(256) void gather_kernel(const int* __restrict__ off,
                                                     const int* __restrict__ csr_src,
                                                     const u16* __restrict__ ts,
                                                     const float* __restrict__ dinv,
                                                     const float* __restrict__ bias,
                                                     float* __restrict__ outh, int N,
                                                     int do_relu) {
    long tid = (long)blockIdx.x * blockDim.x + threadIdx.x;
    int v = (int)(tid >> 6), j = (int)(tid & 63);
    if (v >= N) return;
    int l = j & 7, g = j >> 3;
    const uint4* tp = (const uint4*)ts;  // 8 bf16 per entry, row = 8 entries
    float a0 = 0.f, a1 = 0.f, a2 = 0.f, a3 = 0.f;
    float a4 = 0.f, a5 = 0.f, a6 = 0.f, a7 = 0.f;
    int beg = off[v], end = off[v + 1];
    for (int k = beg + g; k < end; k += 8) {
        int s = csr_src[k];
        uint4 u = tp[((u32)s << 3) + l];
        a0 += __uint_as_float(u.x << 16);
        a1 += __uint_as_float(u.x & 0xffff0000u);
        a2 += __uint_as_float(u.y << 16);
        a3 += __uint_as_float(u.y & 0xffff0000u);
        a4 += __uint_as_float(u.z << 16);
        a5 += __uint_as_float(u.z & 0xffff0000u);
        a6 += __uint_as_float(u.w << 16);
        a7 += __uint_as_float(u.w & 0xffff0000u);
    }
    // combine the 8 groups
#pragma unroll
    for (int o = 8; o < 64; o <<= 1) {
        a0 += __shfl_xor(a0, o, 64);
        a1 += __shfl_xor(a1, o, 64);
        a2 += __shfl_xor(a2, o, 64);
        a3 += __shfl_xor(a3, o, 64);
        a4 += __shfl_xor(a4, o, 64);
        a5 += __shfl_xor(a5, o, 64);
        a6 += __shfl_xor(a6, o, 64);
        a7 += __shfl_xor(a7, o, 64);
    }
    // self-loop term + epilogue
    uint4 su = tp[((u32)v << 3) + l];
    a0 += __uint_as_float(su.x << 16);
    a1 += __uint_as_float(su.x & 0xffff0000u);
    a2 += __uint_as_float(su.y << 16);
    a3 += __uint_as_float(su.y & 0xffff0000u);
    a4 += __uint_as_float(su.z << 16);
    a5 += __uint_as_float(su.z & 0xffff0000u);
    a6 += __uint_as_float(su.w << 16);
    a7 += __uint_as_float(su.w & 0xffff0000u);
    float dv = dinv[v];
    const float* bp = bias + 8 * l;
    float4 b4a = *(const float4*)(bp);
    float4 b4b = *(const float4*)(bp + 4);
    float4 r0, r1;
    r0.x = a0 * dv + b4a.x; r0.y = a1 * dv + b4a.y;
    r0.z = a2 * dv + b4a.z; r0.w = a3 * dv + b4a.w;
    r1.x = a4 * dv + b4b.x; r1.y = a5 * dv + b4b.y;
    r1.z = a6 * dv + b4b.z; r1.w = a7 * dv + b4b.w;
    if (do_relu) {
        r0.x = fmaxf(r0.x, 0.f); r0.y = fmaxf(r0.y, 0.f);
        r0.z = fmaxf(r0.z, 0.f); r0.w = fmaxf(r0.w, 0.f);
        r1.x = fmaxf(r1.x, 0.f); r1.y = fmaxf(r1.y, 0.f);
        r1.z = fmaxf(r1.z, 0.f); r1.w = fmaxf(r1.w, 0.f);
    }
    if (g == 0) {
        float* op = outh + ((u32)v << 6) + 8 * l;
        *(float4*)(op) = r0;
        *(float4*)(op + 4) = r1;
    }
}

// ---------------- node-centric decode: 8 edges/pass, 8 features/lane ----------------
__global__ __launch_bounds__(256) void decode_kernel(const int* __restrict__ off,
                                                     const int* __restrict__ csr_src,
                                                     const int* __restrict__ csr_eid,
                                                     const u16* __restrict__ a,
                                                     const float* __restrict__ c,
                                                     const float* __restrict__ Wl2,
                                                     const float* __restrict__ bl2,
                                                     float* __restrict__ out, int N) {
    long tid = (long)blockIdx.x * blockDim.x + threadIdx.x;
    int v = (int)(tid >> 6), j = (int)(tid & 63);
    if (v >= N) return;
    int l = j & 7, g = j >> 3;
    const float* cv = c + ((u32)v << 6) + 8 * l;
    float4 ca = *(const float4*)(cv);
    float4 cb = *(const float4*)(cv + 4);
    const float* wv = Wl2 + 8 * l;
    float4 wa = *(const float4*)(wv);
    float4 wb = *(const float4*)(wv + 4);
    float bl2v = bl2[0];
    const uint4* ap = (const uint4*)a;
    int beg = off[v], end = off[v + 1];
    for (int k = beg + g; ; k += 8) {
        bool act = k < end;
        if (!__any(act)) break;
        float p = 0.f;
        int eid = 0;
        if (act) {
            int s = csr_src[k];
            eid = csr_eid[k];
            uint4 u = ap[((u32)s << 3) + l];
            float f0 = __uint_as_float(u.x << 16);
            float f1 = __uint_as_float(u.x & 0xffff0000u);
            float f2 = __uint_as_float(u.y << 16);
            float f3 = __uint_as_float(u.y & 0xffff0000u);
            float f4 = __uint_as_float(u.z << 16);
            float f5 = __uint_as_float(u.z & 0xffff0000u);
            float f6 = __uint_as_float(u.w << 16);
            float f7 = __uint_as_float(u.w & 0xffff0000u);
            p  = fmaxf(f0 + ca.x, 0.f) * wa.x;
            p += fmaxf(f1 + ca.y, 0.f) * wa.y;
            p += fmaxf(f2 + ca.z, 0.f) * wa.z;
            p += fmaxf(f3 + ca.w, 0.f) * wa.w;
            p += fmaxf(f4 + cb.x, 0.f) * wb.x;
            p += fmaxf(f5 + cb.y, 0.f) * wb.y;
            p += fmaxf(f6 + cb.z, 0.f) * wb.z;
            p += fmaxf(f7 + cb.w, 0.f) * wb.w;
        }
        // 3-step reduce within the 8-lane group
        p += __shfl_xor(p, 1, 64);
        p += __shfl_xor(p, 2, 64);
        p += __shfl_xor(p, 4, 64);
        if (act && l == 0) {
            float t = __expf(-(p + bl2v));
            out[eid] = __builtin_amdgcn_rcpf(1.f + t);
        }
    }
}

extern "C" void kernel_launch(void* const* d_in, const int* in_sizes, int n_in,
                              void* d_out, int out_size, void* d_ws, size_t ws_size,
                              hipStream_t stream) {
    const float* x   = (const float*)d_in[0];
    const int*   ei  = (const int*)d_in[1];
    const float* W1  = (const float*)d_in[2];
    const float* b1  = (const float*)d_in[3];
    const float* W2  = (const float*)d_in[4];
    const float* b2  = (const float*)d_in[5];
    const float* Wl1 = (const float*)d_in[6];
    const float* bl1 = (const float*)d_in[7];
    const float* Wl2 = (const float*)d_in[8];
    const float* bl2 = (const float*)d_in[9];
    float* out = (float*)d_out;

    const int N = in_sizes[0] / IN_DIM;   // 100000
    const int E = in_sizes[1] / 2;        // 3200000
    const int* src = ei;
    const int* dst = ei + E;

    // workspace layout
    char* ws = (char*)d_ws;
    int*   off     = (int*)ws;    ws += (size_t)(N + 64) * 4;
    float* dinv    = (float*)ws;  ws += (size_t)(N + 64) * 4;
    int*   bhist   = (int*)ws;    ws += 1024;
    int*   bbase   = (int*)ws;    ws += 1024 + 64;
    int*   bcur    = (int*)ws;    ws += 1024;
    int*   csr_src = (int*)ws;    ws += (size_t)E * 4;
    int*   csr_eid = (int*)ws;    ws += (size_t)E * 4;
    u16*   tb      = (u16*)ws;    ws += (size_t)N * HID * 2;   // t1, t2, then a (bf16)
    float* h       = (float*)ws;  ws += (size_t)N * HID * 4;   // h, then z
    float* c       = (float*)ws;  ws += (size_t)N * HID * 4;
    int2*  bpair   = (int2*)h;    // overlay: E*8 == N*HID*4, dead before gather1

    const int TPB = 256;
    long nodeT = (long)N * HID;
    int nodeBlocks = (int)((nodeT + TPB - 1) / TPB);
    int tBlocks = (E + TILE - 1) / TILE;
    int gBlocks = (N + 63) / 64;

    // ---- CSR build ----
    hipMemsetAsync(bhist, 0, NB * sizeof(int), stream);
    bucket_hist<<<tBlocks, TPB, 0, stream>>>(dst, E, bhist);
    bscan<<<1, 64, 0, stream>>>(bhist, bbase, bcur, off, N, E);
    bucket_fill<<<tBlocks, TPB, 0, stream>>>(src, dst, bcur, bpair, E);
    csr_scatter<<<NB, TPB, 0, stream>>>(bbase, bpair, csr_src, csr_eid, off, dinv, N);

    // ---- conv1: t1 = bf16((x@W1)*dinv) ; h = relu(gather + b1) ----
    mfma_gemm<IN_DIM, 64, 0><<<gBlocks, TPB, 0, stream>>>(x, W1, dinv, nullptr, tb, nullptr, N);
    gather_kernel<<<nodeBlocks, TPB, 0, stream>>>(off, csr_src, tb, dinv, b1, h, N, 1);

    // ---- conv2: t2 = bf16((h@W2)*dinv) ; z = gather + b2 (into h) ----
    mfma_gemm<HID, 64, 0><<<gBlocks, TPB, 0, stream>>>(h, W2, dinv, nullptr, tb, nullptr, N);
    gather_kernel<<<nodeBlocks, TPB, 0, stream>>>(off, csr_src, tb, dinv, b2, h, N, 0);

    // ---- decoder precompute: a = bf16(z@Wl1_top) into tb, c = z@Wl1_bot + bl1 ----
    mfma_gemm<HID, 128, 2><<<gBlocks, TPB, 0, stream>>>(h, Wl1, nullptr, bl1, tb, c, N);

    // ---- node-centric decode ----
    decode_kernel<<<nodeBlocks, TPB, 0, stream>>>(off, csr_src, csr_eid, tb, c, Wl2, bl2, out, N);
}

// Round 9
// 570.541 us; speedup vs baseline: 4.6256x; 1.0237x over previous
//
#include <hip/hip_runtime.h>
#include <hip/hip_bf16.h>
#include <math.h>

#define HID 64
#define IN_DIM 256
#define NPB 400          // nodes per bucket
#define NPB_PAD 448      // padded to multiple of 64 for the in-LDS scan
#define NB  250          // buckets (N/NPB)
#define TILE 8192        // edges per tile block

typedef unsigned short u16;
typedef unsigned int u32;

using bf16x8 = __attribute__((ext_vector_type(8))) short;
using f32x4  = __attribute__((ext_vector_type(4))) float;

__device__ __forceinline__ float bf2f(u16 v) {
    return __uint_as_float((u32)v << 16);
}
__device__ __forceinline__ u16 f2bf(float f) {
    __hip_bfloat16 b = __float2bfloat16(f);  // RNE
    return *(u16*)&b;
}

// ---------------- pass 0: bucket histogram ----------------
__global__ __launch_bounds__(256) void bucket_hist(const int* __restrict__ dst, int E,
                                                   int* __restrict__ bhist) {
    __shared__ int hist[NB];
    int tid = threadIdx.x;
    int base = blockIdx.x * TILE;
    for (int i = tid; i < NB; i += 256) hist[i] = 0;
    __syncthreads();
    for (int i = 0; i < TILE / 256; ++i) {
        int e = base + i * 256 + tid;
        if (e < E) atomicAdd(&hist[dst[e] / NPB], 1);
    }
    __syncthreads();
    for (int b = tid; b < NB; b += 256)
        if (hist[b]) atomicAdd(&bhist[b], hist[b]);
}

// ---------------- bucket scan (1 block) ----------------
__global__ __launch_bounds__(64) void bscan(const int* __restrict__ bhist,
                                            int* __restrict__ bbase,
                                            int* __restrict__ bcur,
                                            int* __restrict__ off, int N, int E) {
    if (threadIdx.x == 0) {
        int run = 0;
        for (int b = 0; b < NB; ++b) {
            bbase[b] = run;
            bcur[b] = run;
            run += bhist[b];
        }
        bbase[NB] = run;
        off[N] = E;
    }
}

// ---------------- pass 1: multisplit edges into dst-range buckets ----------------
// bpair[slot] = {src, dstLocal<<22 | eid}
__global__ __launch_bounds__(256) void bucket_fill(const int* __restrict__ src,
                                                   const int* __restrict__ dst,
                                                   int* __restrict__ bcur,
                                                   int2* __restrict__ bpair, int E) {
    __shared__ int hist[NB], cnt2[NB], gbase[NB];
    int tid = threadIdx.x;
    int base = blockIdx.x * TILE;
    for (int i = tid; i < NB; i += 256) { hist[i] = 0; cnt2[i] = 0; }
    __syncthreads();
    for (int i = 0; i < TILE / 256; ++i) {
        int e = base + i * 256 + tid;
        if (e < E) atomicAdd(&hist[dst[e] / NPB], 1);
    }
    __syncthreads();
    for (int b = tid; b < NB; b += 256)
        if (hist[b]) gbase[b] = atomicAdd(&bcur[b], hist[b]);
    __syncthreads();
    for (int i = 0; i < TILE / 256; ++i) {
        int e = base + i * 256 + tid;
        if (e < E) {
            int d = dst[e];
            int b = d / NPB;
            int lp = atomicAdd(&cnt2[b], 1);
            bpair[gbase[b] + lp] = make_int2(src[e], ((d - b * NPB) << 22) | e);
        }
    }
}

// ---------------- pass 2: within-bucket counting sort -> CSR + off + dinv ----------------
__global__ __launch_bounds__(256) void csr_scatter(const int* __restrict__ bbase,
                                                   const int2* __restrict__ bpair,
                                                   int* __restrict__ csr_src,
                                                   int* __restrict__ csr_eid,
                                                   int* __restrict__ off,
                                                   float* __restrict__ dinv, int N) {
    __shared__ int cnt[NPB_PAD];   // padded: scan reads/writes [0,448) in-bounds
    __shared__ int cur[NPB_PAD];
    int tid = threadIdx.x;
    int b = blockIdx.x;
    int node0 = b * NPB;
    int beg = bbase[b], end = bbase[b + 1];
    for (int i = tid; i < NPB_PAD; i += 256) cnt[i] = 0;
    __syncthreads();
    for (int i = beg + tid; i < end; i += 256)
        atomicAdd(&cnt[(bpair[i].y >> 22) & 511], 1);
    __syncthreads();
    // wave 0: exclusive scan of cnt -> cur (base = beg); padding lanes are zeros
    if (tid < 64) {
        int lane = tid;
        int carry = beg;
#pragma unroll
        for (int c0 = 0; c0 < NPB_PAD; c0 += 64) {
            int v = cnt[c0 + lane];
            int incl = v;
#pragma unroll
            for (int s = 1; s < 64; s <<= 1) {
                int t = __shfl_up(incl, s, 64);
                if (lane >= s) incl += t;
            }
            cur[c0 + lane] = carry + incl - v;
            carry += __shfl(incl, 63, 64);
        }
    }
    __syncthreads();
    for (int i = tid; i < NPB; i += 256) {
        off[node0 + i] = cur[i];
        dinv[node0 + i] = rsqrtf((float)cnt[i] + 1.0f);
    }
    __syncthreads();
    for (int i = beg + tid; i < end; i += 256) {
        int2 p = bpair[i];
        int dl = (p.y >> 22) & 511;
        int pos = atomicAdd(&cur[dl], 1);
        csr_src[pos] = p.x;
        csr_eid[pos] = p.y & 0x3FFFFF;
    }
}

// ---------------- MFMA GEMM: out = A[N,K] @ W[K,COLS] (hi/lo split, fp32-accurate) ----
template<int K, int COLS, int MODE>
__global__ __launch_bounds__(256) void mfma_gemm(const float* __restrict__ A,
                                                 const float* __restrict__ W,
                                                 const float* __restrict__ dinv,
                                                 const float* __restrict__ bias,
                                                 u16* __restrict__ out_b,
                                                 float* __restrict__ out_f,
                                                 int N) {
    constexpr int KP = K + 8;
    constexpr int AP = 72;
    constexpr int NT = COLS / 16;
    __shared__ __align__(16) u16 Wh[COLS * KP];
    __shared__ __align__(16) u16 Wl[COLS * KP];
    __shared__ __align__(16) u16 Ah[64 * AP];
    __shared__ __align__(16) u16 Al[64 * AP];

    const int tid  = threadIdx.x;
    const int wave = tid >> 6;
    const int lane = tid & 63;
    const int lr   = lane & 15;
    const int kg   = lane >> 4;
    const int row0 = blockIdx.x * 64;

    for (int e = tid; e < K * COLS; e += 256) {
        int k = e / COLS, c = e % COLS;
        int gidx = (MODE == 2) ? (((c >> 6) * K + k) * 64 + (c & 63)) : e;
        float f = W[gidx];
        u16 hi = f2bf(f);
        u16 lo = f2bf(f - bf2f(hi));
        Wh[c * KP + k] = hi;
        Wl[c * KP + k] = lo;
    }

    f32x4 acc[NT];
#pragma unroll
    for (int c = 0; c < NT; ++c) acc[c] = (f32x4){0.f, 0.f, 0.f, 0.f};

    for (int kc = 0; kc < K; kc += 64) {
        __syncthreads();
#pragma unroll
        for (int it = 0; it < 4; ++it) {
            int idx = it * 256 + tid;
            int r  = idx >> 4;
            int k4 = (idx & 15) * 4;
            int gr = row0 + r;
            float4 v = make_float4(0.f, 0.f, 0.f, 0.f);
            if (gr < N) v = *(const float4*)(A + (size_t)gr * K + kc + k4);
            u16 h0 = f2bf(v.x), h1 = f2bf(v.y), h2 = f2bf(v.z), h3 = f2bf(v.w);
            ushort4 hv = make_ushort4(h0, h1, h2, h3);
            ushort4 lv = make_ushort4(f2bf(v.x - bf2f(h0)), f2bf(v.y - bf2f(h1)),
                                      f2bf(v.z - bf2f(h2)), f2bf(v.w - bf2f(h3)));
            *(ushort4*)(Ah + r * AP + k4) = hv;
            *(ushort4*)(Al + r * AP + k4) = lv;
        }
        __syncthreads();
#pragma unroll
        for (int ks = 0; ks < 64; ks += 32) {
            const int arow = wave * 16 + lr;
            bf16x8 ah = *(const bf16x8*)(Ah + arow * AP + ks + kg * 8);
            bf16x8 al = *(const bf16x8*)(Al + arow * AP + ks + kg * 8);
#pragma unroll
            for (int c = 0; c < NT; ++c) {
                const int wrow = c * 16 + lr;
                bf16x8 bh = *(const bf16x8*)(Wh + wrow * KP + kc + ks + kg * 8);
                bf16x8 bl = *(const bf16x8*)(Wl + wrow * KP + kc + ks + kg * 8);
                acc[c] = __builtin_amdgcn_mfma_f32_16x16x32_bf16(ah, bh, acc[c], 0, 0, 0);
                acc[c] = __builtin_amdgcn_mfma_f32_16x16x32_bf16(ah, bl, acc[c], 0, 0, 0);
                acc[c] = __builtin_amdgcn_mfma_f32_16x16x32_bf16(al, bh, acc[c], 0, 0, 0);
            }
        }
    }

#pragma unroll
    for (int rr = 0; rr < 4; ++rr) {
        int n = row0 + wave * 16 + kg * 4 + rr;
        if (n >= N) continue;
        float dv = (MODE == 0) ? dinv[n] : 1.f;
#pragma unroll
        for (int c = 0; c < NT; ++c) {
            int col = c * 16 + lr;
            float v = acc[c][rr];
            if (MODE == 0) {
                out_b[(size_t)n * 64 + col] = f2bf(v * dv);
            } else {
                if (col < 64) out_b[(size_t)n * 64 + col] = f2bf(v);
                else out_f[(size_t)n * 64 + (col - 64)] = v + bias[col - 64];
            }
        }
    }
}

// ---------------- gather: 8 features/lane, 4-deep pipelined edge loop ----------------
// h[v] = relu?( dinv[v]*(sum_in ts[s] + ts[v]) + bias )
__global__ __launch_bounds__(256) void gather_kernel(const int* __restrict__ off,
                                                     const int* __restrict__ csr_src,
                                                     const u16* __restrict__ ts,
                                                     const float* __restrict__ dinv,
                                                     const float* __restrict__ bias,
                                                     float* __restrict__ outh, int N,
                                                     int do_relu) {
    long tid = (long)blockIdx.x * blockDim.x + threadIdx.x;
    int v = (int)(tid >> 6), j = (int)(tid & 63);
    if (v >= N) return;
    int l = j & 7, g = j >> 3;
    const uint4* tp = (const uint4*)ts;  // 8 bf16 per entry, row = 8 entries
    float a0 = 0.f, a1 = 0.f, a2 = 0.f, a3 = 0.f;
    float a4 = 0.f, a5 = 0.f, a6 = 0.f, a7 = 0.f;
    int beg = off[v], end = off[v + 1];

#define ACCUM(U)                              \
    a0 += __uint_as_float((U).x << 16);       \
    a1 += __uint_as_float((U).x & 0xffff0000u); \
    a2 += __uint_as_float((U).y << 16);       \
    a3 += __uint_as_float((U).y & 0xffff0000u); \
    a4 += __uint_as_float((U).z << 16);       \
    a5 += __uint_as_float((U).z & 0xffff0000u); \
    a6 += __uint_as_float((U).w << 16);       \
    a7 += __uint_as_float((U).w & 0xffff0000u);

    int k = beg + g;
    while (k + 24 < end) {   // 4 edges for this group in flight
        int s0 = csr_src[k];
        int s1 = csr_src[k + 8];
        int s2 = csr_src[k + 16];
        int s3 = csr_src[k + 24];
        uint4 u0 = tp[((u32)s0 << 3) + l];
        uint4 u1 = tp[((u32)s1 << 3) + l];
        uint4 u2 = tp[((u32)s2 << 3) + l];
        uint4 u3 = tp[((u32)s3 << 3) + l];
        ACCUM(u0); ACCUM(u1); ACCUM(u2); ACCUM(u3);
        k += 32;
    }
    while (k < end) {
        int s = csr_src[k];
        uint4 u = tp[((u32)s << 3) + l];
        ACCUM(u);
        k += 8;
    }
    // combine the 8 groups
#pragma unroll
    for (int o = 8; o < 64; o <<= 1) {
        a0 += __shfl_xor(a0, o, 64);
        a1 += __shfl_xor(a1, o, 64);
        a2 += __shfl_xor(a2, o, 64);
        a3 += __shfl_xor(a3, o, 64);
        a4 += __shfl_xor(a4, o, 64);
        a5 += __shfl_xor(a5, o, 64);
        a6 += __shfl_xor(a6, o, 64);
        a7 += __shfl_xor(a7, o, 64);
    }
    // self-loop term + epilogue
    uint4 su = tp[((u32)v << 3) + l];
    ACCUM(su);
#undef ACCUM
    float dv = dinv[v];
    const float* bp = bias + 8 * l;
    float4 b4a = *(const float4*)(bp);
    float4 b4b = *(const float4*)(bp + 4);
    float4 r0, r1;
    r0.x = a0 * dv + b4a.x; r0.y = a1 * dv + b4a.y;
    r0.z = a2 * dv + b4a.z; r0.w = a3 * dv + b4a.w;
    r1.x = a4 * dv + b4b.x; r1.y = a5 * dv + b4b.y;
    r1.z = a6 * dv + b4b.z; r1.w = a7 * dv + b4b.w;
    if (do_relu) {
        r0.x = fmaxf(r0.x, 0.f); r0.y = fmaxf(r0.y, 0.f);
        r0.z = fmaxf(r0.z, 0.f); r0.w = fmaxf(r0.w, 0.f);
        r1.x = fmaxf(r1.x, 0.f); r1.y = fmaxf(r1.y, 0.f);
        r1.z = fmaxf(r1.z, 0.f); r1.w = fmaxf(r1.w, 0.f);
    }
    if (g == 0) {
        float* op = outh + ((u32)v << 6) + 8 * l;
        *(float4*)(op) = r0;
        *(float4*)(op + 4) = r1;
    }
}

// ---------------- node-centric decode: 8 features/lane, 2-deep pipelined ----------------
__global__ __launch_bounds__(256) void decode_kernel(const int* __restrict__ off,
                                                     const int* __restrict__ csr_src,
                                                     const int* __restrict__ csr_eid,
                                                     const u16* __restrict__ a,
                                                     const float* __restrict__ c,
                                                     const float* __restrict__ Wl2,
                                                     const float* __restrict__ bl2,
                                                     float* __restrict__ out, int N) {
    long tid = (long)blockIdx.x * blockDim.x + threadIdx.x;
    int v = (int)(tid >> 6), j = (int)(tid & 63);
    if (v >= N) return;
    int l = j & 7, g = j >> 3;
    const float* cv = c + ((u32)v << 6) + 8 * l;
    float4 ca = *(const float4*)(cv);
    float4 cb = *(const float4*)(cv + 4);
    const float* wv = Wl2 + 8 * l;
    float4 wa = *(const float4*)(wv);
    float4 wb = *(const float4*)(wv + 4);
    float bl2v = bl2[0];
    const uint4* ap = (const uint4*)a;
    int beg = off[v], end = off[v + 1];

#define EDGEP(U, P)                                                   \
    {                                                                 \
        float f0 = __uint_as_float((U).x << 16);                      \
        float f1 = __uint_as_float((U).x & 0xffff0000u);              \
        float f2 = __uint_as_float((U).y << 16);                      \
        float f3 = __uint_as_float((U).y & 0xffff0000u);              \
        float f4 = __uint_as_float((U).z << 16);                      \
        float f5 = __uint_as_float((U).z & 0xffff0000u);              \
        float f6 = __uint_as_float((U).w << 16);                      \
        float f7 = __uint_as_float((U).w & 0xffff0000u);              \
        P  = fmaxf(f0 + ca.x, 0.f) * wa.x;                            \
        P += fmaxf(f1 + ca.y, 0.f) * wa.y;                            \
        P += fmaxf(f2 + ca.z, 0.f) * wa.z;                            \
        P += fmaxf(f3 + ca.w, 0.f) * wa.w;                            \
        P += fmaxf(f4 + cb.x, 0.f) * wb.x;                            \
        P += fmaxf(f5 + cb.y, 0.f) * wb.y;                            \
        P += fmaxf(f6 + cb.z, 0.f) * wb.z;                            \
        P += fmaxf(f7 + cb.w, 0.f) * wb.w;                            \
    }

    int k = beg + g;
    while (k + 8 < end) {   // 2 edges for this group in flight
        int s0 = csr_src[k];
        int s1 = csr_src[k + 8];
        int e0 = csr_eid[k];
        int e1 = csr_eid[k + 8];
        uint4 u0 = ap[((u32)s0 << 3) + l];
        uint4 u1 = ap[((u32)s1 << 3) + l];
        float p0, p1;
        EDGEP(u0, p0);
        EDGEP(u1, p1);
        p0 += __shfl_xor(p0, 1, 64);
        p1 += __shfl_xor(p1, 1, 64);
        p0 += __shfl_xor(p0, 2, 64);
        p1 += __shfl_xor(p1, 2, 64);
        p0 += __shfl_xor(p0, 4, 64);
        p1 += __shfl_xor(p1, 4, 64);
        if (l == 0) {
            out[e0] = __builtin_amdgcn_rcpf(1.f + __expf(-(p0 + bl2v)));
            out[e1] = __builtin_amdgcn_rcpf(1.f + __expf(-(p1 + bl2v)));
        }
        k += 16;
    }
    if (k < end) {
        int s0 = csr_src[k];
        int e0 = csr_eid[k];
        uint4 u0 = ap[((u32)s0 << 3) + l];
        float p0;
        EDGEP(u0, p0);
        p0 += __shfl_xor(p0, 1, 64);
        p0 += __shfl_xor(p0, 2, 64);
        p0 += __shfl_xor(p0, 4, 64);
        if (l == 0) out[e0] = __builtin_amdgcn_rcpf(1.f + __expf(-(p0 + bl2v)));
    }
#undef EDGEP
}

extern "C" void kernel_launch(void* const* d_in, const int* in_sizes, int n_in,
                              void* d_out, int out_size, void* d_ws, size_t ws_size,
                              hipStream_t stream) {
    const float* x   = (const float*)d_in[0];
    const int*   ei  = (const int*)d_in[1];
    const float* W1  = (const float*)d_in[2];
    const float* b1  = (const float*)d_in[3];
    const float* W2  = (const float*)d_in[4];
    const float* b2  = (const float*)d_in[5];
    const float* Wl1 = (const float*)d_in[6];
    const float* bl1 = (const float*)d_in[7];
    const float* Wl2 = (const float*)d_in[8];
    const float* bl2 = (const float*)d_in[9];
    float* out = (float*)d_out;

    const int N = in_sizes[0] / IN_DIM;   // 100000
    const int E = in_sizes[1] / 2;        // 3200000
    const int* src = ei;
    const int* dst = ei + E;

    // workspace layout
    char* ws = (char*)d_ws;
    int*   off     = (int*)ws;    ws += (size_t)(N + 64) * 4;
    float* dinv    = (float*)ws;  ws += (size_t)(N + 64) * 4;
    int*   bhist   = (int*)ws;    ws += 1024;
    int*   bbase   = (int*)ws;    ws += 1024 + 64;
    int*   bcur    = (int*)ws;    ws += 1024;
    int*   csr_src = (int*)ws;    ws += (size_t)E * 4;
    int*   csr_eid = (int*)ws;    ws += (size_t)E * 4;
    u16*   tb      = (u16*)ws;    ws += (size_t)N * HID * 2;   // t1, t2, then a (bf16)
    float* h       = (float*)ws;  ws += (size_t)N * HID * 4;   // h, then z
    float* c       = (float*)ws;  ws += (size_t)N * HID * 4;
    int2*  bpair   = (int2*)h;    // overlay: E*8 == N*HID*4 exactly, dead before gather1

    const int TPB = 256;
    long nodeT = (long)N * HID;
    int nodeBlocks = (int)((nodeT + TPB - 1) / TPB);
    int tBlocks = (E + TILE - 1) / TILE;
    int gBlocks = (N + 63) / 64;

    // ---- CSR build (r6-proven: hist -> scan -> fill -> scatter) ----
    hipMemsetAsync(bhist, 0, NB * sizeof(int), stream);
    bucket_hist<<<tBlocks, TPB, 0, stream>>>(dst, E, bhist);
    bscan<<<1, 64, 0, stream>>>(bhist, bbase, bcur, off, N, E);
    bucket_fill<<<tBlocks, TPB, 0, stream>>>(src, dst, bcur, bpair, E);
    csr_scatter<<<NB, TPB, 0, stream>>>(bbase, bpair, csr_src, csr_eid, off, dinv, N);

    // ---- conv1: t1 = bf16((x@W1)*dinv) ; h = relu(gather + b1) ----
    mfma_gemm<IN_DIM, 64, 0><<<gBlocks, TPB, 0, stream>>>(x, W1, dinv, nullptr, tb, nullptr, N);
    gather_kernel<<<nodeBlocks, TPB, 0, stream>>>(off, csr_src, tb, dinv, b1, h, N, 1);

    // ---- conv2: t2 = bf16((h@W2)*dinv) ; z = gather + b2 (into h) ----
    mfma_gemm<HID, 64, 0><<<gBlocks, TPB, 0, stream>>>(h, W2, dinv, nullptr, tb, nullptr, N);
    gather_kernel<<<nodeBlocks, TPB, 0, stream>>>(off, csr_src, tb, dinv, b2, h, N, 0);

    // ---- decoder precompute: a = bf16(z@Wl1_top) into tb, c = z@Wl1_bot + bl1 ----
    mfma_gemm<HID, 128, 2><<<gBlocks, TPB, 0, stream>>>(h, Wl1, nullptr, bl1, tb, c, N);

    // ---- node-centric decode ----
    decode_kernel<<<nodeBlocks, TPB, 0, stream>>>(off, csr_src, csr_eid, tb, c, Wl2, bl2, out, N);
}